// Round 2
// baseline (1597.947 us; speedup 1.0000x reference)
//
#include <hip/hip_runtime.h>
#include <hip/hip_bf16.h>

#define N_NODES 50000
#define N_EDGES 800000
#define N_FEAT 128
#define HIDDEN 256
#define N_GRAPHS 256
#define N_CLASSES 10

// NOTE (harness contract): integer inputs are delivered as int32 regardless of
// the reference's int64 declaration. edge_index is (2, N_EDGES) int32,
// batch is (N_NODES,) int32. Reading them as long long caused the round-1
// GPU memory fault.

// ---------------- CSR build ----------------

__global__ void count_deg_kernel(const int* __restrict__ ei, unsigned* __restrict__ deg) {
    int e = blockIdx.x * blockDim.x + threadIdx.x;
    if (e < N_EDGES) {
        int dst = ei[N_EDGES + e];
        atomicAdd(&deg[dst], 1u);
    }
}

__global__ void scan_kernel(const unsigned* __restrict__ deg, unsigned* __restrict__ rowptr) {
    __shared__ unsigned partial[1024];
    int tid = threadIdx.x;
    const int n = N_NODES;
    int chunk = (n + 1023) / 1024;
    int start = tid * chunk;
    int end = start + chunk; if (end > n) end = n; if (start > n) start = n;
    unsigned s = 0;
    for (int i = start; i < end; i++) s += deg[i];
    partial[tid] = s;
    __syncthreads();
    if (tid == 0) {
        unsigned run = 0;
        for (int i = 0; i < 1024; i++) { unsigned t = partial[i]; partial[i] = run; run += t; }
    }
    __syncthreads();
    unsigned run = partial[tid];
    for (int i = start; i < end; i++) { rowptr[i] = run; run += deg[i]; }
    if (tid == 1023) rowptr[n] = run;
}

__global__ void init_cursor_kernel(const unsigned* __restrict__ rowptr, unsigned* __restrict__ cursor) {
    int i = blockIdx.x * blockDim.x + threadIdx.x;
    if (i < N_NODES) cursor[i] = rowptr[i];
}

__global__ void fill_adj_kernel(const int* __restrict__ ei, unsigned* __restrict__ cursor,
                                int* __restrict__ adj) {
    int e = blockIdx.x * blockDim.x + threadIdx.x;
    if (e < N_EDGES) {
        int src = ei[e];
        int dst = ei[N_EDGES + e];
        unsigned pos = atomicAdd(&cursor[dst], 1u);
        adj[pos] = src;
    }
}

// ---------------- Aggregation: out[n] = (1+eps)*x[n] + sum_{src in N(n)} x[src] ----------------
// blockDim.x == F (128 or 256), one block per node.

__global__ void aggregate_kernel(const float* __restrict__ x, const int* __restrict__ adj,
                                 const unsigned* __restrict__ rowptr,
                                 const float* __restrict__ eps_arr, int eps_idx,
                                 float* __restrict__ out, int F) {
    int n = blockIdx.x;
    int t = threadIdx.x;
    unsigned beg = rowptr[n], end = rowptr[n + 1];
    float acc = 0.f;
    for (unsigned e = beg; e < end; e++) {
        int s = adj[e];
        acc += x[(size_t)s * F + t];
    }
    float eps = eps_arr[eps_idx];
    out[(size_t)n * F + t] = (1.f + eps) * x[(size_t)n * F + t] + acc;
}

// ---------------- GEMM: C = act(A[MxK] @ W[KxN=256] + b), optional eval-BN ----------------
// BM=64, BN=64, BK=16, 256 threads, 4x4 microtile.

#define BM 64
#define BN 64
#define BK 16

__global__ __launch_bounds__(256) void gemm_kernel(
    const float* __restrict__ A, const float* __restrict__ W, const float* __restrict__ bias,
    float* __restrict__ C, int M, int K,
    const float* __restrict__ bn_g, const float* __restrict__ bn_b,
    const float* __restrict__ bn_m, const float* __restrict__ bn_v, int do_bn)
{
    __shared__ float As[BK][BM + 4];
    __shared__ float Ws[BK][BN];

    int tid = threadIdx.x;
    int tx = tid & 15, ty = tid >> 4;
    int row0 = blockIdx.x * BM;
    int col0 = blockIdx.y * BN;

    int ar = tid >> 2, akq = tid & 3;     // A tile load: row ar (0..63), k-quad akq (0..3)
    int wk = tid >> 4, wnq = tid & 15;    // W tile load: k wk (0..15), n-quad wnq (0..15)

    float acc[4][4];
    #pragma unroll
    for (int i = 0; i < 4; i++)
        #pragma unroll
        for (int j = 0; j < 4; j++) acc[i][j] = 0.f;

    for (int k0 = 0; k0 < K; k0 += BK) {
        int arow = row0 + ar;
        float4 av = make_float4(0.f, 0.f, 0.f, 0.f);
        if (arow < M) av = *reinterpret_cast<const float4*>(A + (size_t)arow * K + k0 + akq * 4);
        As[akq * 4 + 0][ar] = av.x;
        As[akq * 4 + 1][ar] = av.y;
        As[akq * 4 + 2][ar] = av.z;
        As[akq * 4 + 3][ar] = av.w;

        float4 wv = *reinterpret_cast<const float4*>(W + (size_t)(k0 + wk) * HIDDEN + col0 + wnq * 4);
        *reinterpret_cast<float4*>(&Ws[wk][wnq * 4]) = wv;

        __syncthreads();
        #pragma unroll
        for (int kk = 0; kk < BK; kk++) {
            float4 a4 = *reinterpret_cast<const float4*>(&As[kk][ty * 4]);
            float4 w4 = *reinterpret_cast<const float4*>(&Ws[kk][tx * 4]);
            float a[4] = {a4.x, a4.y, a4.z, a4.w};
            float w[4] = {w4.x, w4.y, w4.z, w4.w};
            #pragma unroll
            for (int i = 0; i < 4; i++)
                #pragma unroll
                for (int j = 0; j < 4; j++) acc[i][j] += a[i] * w[j];
        }
        __syncthreads();
    }

    #pragma unroll
    for (int i = 0; i < 4; i++) {
        int r = row0 + ty * 4 + i;
        if (r >= M) continue;
        #pragma unroll
        for (int j = 0; j < 4; j++) {
            int c = col0 + tx * 4 + j;
            float v = acc[i][j] + bias[c];
            v = fmaxf(v, 0.f);
            if (do_bn) v = (v - bn_m[c]) * rsqrtf(bn_v[c] + 1e-5f) * bn_g[c] + bn_b[c];
            C[(size_t)r * HIDDEN + c] = v;
        }
    }
}

// ---------------- Pool: per-graph mean over sorted batch ids ----------------

__global__ void pool_kernel(const float* __restrict__ h, const int* __restrict__ batch,
                            float* __restrict__ pooled) {
    int g = blockIdx.x;
    __shared__ int sbeg, send;
    if (threadIdx.x == 0) {
        int lo = 0, hi = N_NODES;
        while (lo < hi) { int mid = (lo + hi) >> 1; if (batch[mid] < g) lo = mid + 1; else hi = mid; }
        sbeg = lo;
        hi = N_NODES;
        while (lo < hi) { int mid = (lo + hi) >> 1; if (batch[mid] < g + 1) lo = mid + 1; else hi = mid; }
        send = lo;
    }
    __syncthreads();
    int t = threadIdx.x;
    float s = 0.f;
    for (int n = sbeg; n < send; n++) s += h[(size_t)n * HIDDEN + t];
    float cnt = (float)(send - sbeg);
    pooled[g * HIDDEN + t] = s / fmaxf(cnt, 1.f);
}

// ---------------- Head: relu(pooled@lin1+b1) @ lin2 + b2 -> log_softmax ----------------

__global__ void head_kernel(const float* __restrict__ pooled,
                            const float* __restrict__ w1, const float* __restrict__ b1,
                            const float* __restrict__ w2, const float* __restrict__ b2,
                            float* __restrict__ out) {
    int g = blockIdx.x, t = threadIdx.x;
    __shared__ float p[HIDDEN];
    __shared__ float h1[HIDDEN];
    __shared__ float lg[N_CLASSES];
    p[t] = pooled[g * HIDDEN + t];
    __syncthreads();
    float acc = b1[t];
    for (int k = 0; k < HIDDEN; k++) acc += p[k] * w1[k * HIDDEN + t];
    h1[t] = fmaxf(acc, 0.f);
    __syncthreads();
    if (t < N_CLASSES) {
        float a = b2[t];
        for (int k = 0; k < HIDDEN; k++) a += h1[k] * w2[k * N_CLASSES + t];
        lg[t] = a;
    }
    __syncthreads();
    if (t == 0) {
        float mx = lg[0];
        for (int j = 1; j < N_CLASSES; j++) mx = fmaxf(mx, lg[j]);
        float se = 0.f;
        for (int j = 0; j < N_CLASSES; j++) se += expf(lg[j] - mx);
        float lse = mx + logf(se);
        for (int j = 0; j < N_CLASSES; j++) out[g * N_CLASSES + j] = lg[j] - lse;
    }
}

// ---------------- Launch ----------------

extern "C" void kernel_launch(void* const* d_in, const int* in_sizes, int n_in,
                              void* d_out, int out_size, void* d_ws, size_t ws_size,
                              hipStream_t stream) {
    const float* x       = (const float*)d_in[0];
    const int*   ei      = (const int*)d_in[1];     // int32 on device (harness contract)
    const int*   batch   = (const int*)d_in[2];     // int32 on device
    const float* c1_w0   = (const float*)d_in[3];
    const float* c1_b0   = (const float*)d_in[4];
    const float* c1_w1   = (const float*)d_in[5];
    const float* c1_b1   = (const float*)d_in[6];
    const float* c1_g    = (const float*)d_in[7];
    const float* c1_be   = (const float*)d_in[8];
    const float* c1_m    = (const float*)d_in[9];
    const float* c1_v    = (const float*)d_in[10];
    const float* cs_w0   = (const float*)d_in[11];
    const float* cs_b0   = (const float*)d_in[12];
    const float* cs_w1   = (const float*)d_in[13];
    const float* cs_b1   = (const float*)d_in[14];
    const float* cs_g    = (const float*)d_in[15];
    const float* cs_be   = (const float*)d_in[16];
    const float* cs_m    = (const float*)d_in[17];
    const float* cs_v    = (const float*)d_in[18];
    const float* eps     = (const float*)d_in[19];
    const float* lin1_w  = (const float*)d_in[20];
    const float* lin1_b  = (const float*)d_in[21];
    const float* lin2_w  = (const float*)d_in[22];
    const float* lin2_b  = (const float*)d_in[23];

    char* ws = (char*)d_ws;
    size_t off = 0;
    auto alloc = [&](size_t bytes) -> void* {
        void* p = ws + off;
        off += (bytes + 255) & ~(size_t)255;
        return p;
    };

    unsigned* deg    = (unsigned*)alloc(N_NODES * 4);
    unsigned* rowptr = (unsigned*)alloc((N_NODES + 1) * 4);
    unsigned* cursor = (unsigned*)alloc(N_NODES * 4);
    int*      adj    = (int*)alloc(N_EDGES * 4);
    float*    B1     = (float*)alloc((size_t)N_NODES * HIDDEN * 4);
    float*    B2     = (float*)alloc((size_t)N_NODES * HIDDEN * 4);
    float*    B3     = (float*)alloc((size_t)N_NODES * HIDDEN * 4);
    float*    pooled = (float*)alloc(N_GRAPHS * HIDDEN * 4);

    hipMemsetAsync(deg, 0, N_NODES * 4, stream);

    int eb = (N_EDGES + 255) / 256;
    count_deg_kernel<<<eb, 256, 0, stream>>>(ei, deg);
    scan_kernel<<<1, 1024, 0, stream>>>(deg, rowptr);
    init_cursor_kernel<<<(N_NODES + 255) / 256, 256, 0, stream>>>(rowptr, cursor);
    fill_adj_kernel<<<eb, 256, 0, stream>>>(ei, cursor, adj);

    dim3 ggrid((N_NODES + BM - 1) / BM, HIDDEN / BN);

    // Layer 1: F=128
    aggregate_kernel<<<N_NODES, N_FEAT, 0, stream>>>(x, adj, rowptr, eps, 0, B1, N_FEAT);
    gemm_kernel<<<ggrid, 256, 0, stream>>>(B1, c1_w0, c1_b0, B2, N_NODES, N_FEAT,
                                           nullptr, nullptr, nullptr, nullptr, 0);
    gemm_kernel<<<ggrid, 256, 0, stream>>>(B2, c1_w1, c1_b1, B3, N_NODES, HIDDEN,
                                           c1_g, c1_be, c1_m, c1_v, 1);

    // Layers 2..4: F=256
    for (int i = 0; i < 3; i++) {
        aggregate_kernel<<<N_NODES, HIDDEN, 0, stream>>>(B3, adj, rowptr, eps, i + 1, B1, HIDDEN);
        gemm_kernel<<<ggrid, 256, 0, stream>>>(B1, cs_w0 + (size_t)i * HIDDEN * HIDDEN,
                                               cs_b0 + i * HIDDEN, B2, N_NODES, HIDDEN,
                                               nullptr, nullptr, nullptr, nullptr, 0);
        gemm_kernel<<<ggrid, 256, 0, stream>>>(B2, cs_w1 + (size_t)i * HIDDEN * HIDDEN,
                                               cs_b1 + i * HIDDEN, B3, N_NODES, HIDDEN,
                                               cs_g + i * HIDDEN, cs_be + i * HIDDEN,
                                               cs_m + i * HIDDEN, cs_v + i * HIDDEN, 1);
    }

    pool_kernel<<<N_GRAPHS, HIDDEN, 0, stream>>>(B3, batch, pooled);
    head_kernel<<<N_GRAPHS, HIDDEN, 0, stream>>>(pooled, lin1_w, lin1_b, lin2_w, lin2_b, (float*)d_out);
}

// Round 3
// 711.730 us; speedup vs baseline: 2.2452x; 2.2452x over previous
//
#include <hip/hip_runtime.h>
#include <hip/hip_bf16.h>

#define N_NODES 50000
#define N_EDGES 800000
#define N_FEAT 128
#define HIDDEN 256
#define N_GRAPHS 256
#define N_CLASSES 10

typedef __hip_bfloat16 bf16_t;
typedef short bf16x8 __attribute__((ext_vector_type(8)));
typedef float f32x4 __attribute__((ext_vector_type(4)));

__device__ inline float bfb2f(short s) {
    unsigned u = ((unsigned)(unsigned short)s) << 16;
    float f; __builtin_memcpy(&f, &u, 4); return f;
}
__device__ inline short f2bfb(float f) {
    bf16_t b = __float2bfloat16(f);
    short s; __builtin_memcpy(&s, &b, 2); return s;
}

// ---------------- CSR build ----------------

__global__ void count_deg_kernel(const int* __restrict__ ei, unsigned* __restrict__ deg) {
    int e = blockIdx.x * blockDim.x + threadIdx.x;
    if (e < N_EDGES) atomicAdd(&deg[ei[N_EDGES + e]], 1u);
}

__global__ void scan_kernel(const unsigned* __restrict__ deg, unsigned* __restrict__ rowptr) {
    __shared__ unsigned partial[1024];
    int tid = threadIdx.x;
    const int n = N_NODES;
    int chunk = (n + 1023) / 1024;
    int start = tid * chunk;
    int end = start + chunk; if (end > n) end = n; if (start > n) start = n;
    unsigned s = 0;
    for (int i = start; i < end; i++) s += deg[i];
    partial[tid] = s;
    __syncthreads();
    if (tid == 0) {
        unsigned run = 0;
        for (int i = 0; i < 1024; i++) { unsigned t = partial[i]; partial[i] = run; run += t; }
    }
    __syncthreads();
    unsigned run = partial[tid];
    for (int i = start; i < end; i++) { rowptr[i] = run; run += deg[i]; }
    if (tid == 1023) rowptr[n] = run;
}

__global__ void init_cursor_kernel(const unsigned* __restrict__ rowptr, unsigned* __restrict__ cursor) {
    int i = blockIdx.x * blockDim.x + threadIdx.x;
    if (i < N_NODES) cursor[i] = rowptr[i];
}

__global__ void fill_adj_kernel(const int* __restrict__ ei, unsigned* __restrict__ cursor,
                                int* __restrict__ adj) {
    int e = blockIdx.x * blockDim.x + threadIdx.x;
    if (e < N_EDGES) {
        int src = ei[e];
        int dst = ei[N_EDGES + e];
        unsigned pos = atomicAdd(&cursor[dst], 1u);
        adj[pos] = src;
    }
}

// ---------------- Weight prep: fp32 W[K][256] -> bf16 Wt[256][K] ----------------
// grid (8,8,8): x = k-tile, y = n-tile, z = matrix id

__global__ __launch_bounds__(256) void prep_weights_kernel(
    const float* __restrict__ c1_w0, const float* __restrict__ c1_w1,
    const float* __restrict__ cs_w0, const float* __restrict__ cs_w1,
    bf16_t* __restrict__ wt)
{
    __shared__ float T[32][33];
    int z = blockIdx.z;
    const float* src; int K; size_t off;
    if (z == 0)      { src = c1_w0; K = N_FEAT;  off = 0; }
    else if (z == 1) { src = c1_w1; K = HIDDEN;  off = 32768; }
    else {
        int i = (z - 2) >> 1;
        src = (((z - 2) & 1) ? cs_w1 : cs_w0) + (size_t)i * HIDDEN * HIDDEN;
        K = HIDDEN;
        off = 32768 + (size_t)(z - 1) * 65536;
    }
    int k0 = blockIdx.x * 32, n0 = blockIdx.y * 32;
    if (k0 >= K) return;
    int t = threadIdx.x;
    int r = t >> 3, c4 = (t & 7) * 4;
    float4 v = *reinterpret_cast<const float4*>(src + (size_t)(k0 + r) * HIDDEN + n0 + c4);
    T[r][c4 + 0] = v.x; T[r][c4 + 1] = v.y; T[r][c4 + 2] = v.z; T[r][c4 + 3] = v.w;
    __syncthreads();
    int n = t >> 3, kc = (t & 7) * 4;
    short4 o;
    o.x = f2bfb(T[kc + 0][n]); o.y = f2bfb(T[kc + 1][n]);
    o.z = f2bfb(T[kc + 2][n]); o.w = f2bfb(T[kc + 3][n]);
    *reinterpret_cast<short4*>((short*)wt + off + (size_t)(n0 + n) * K + k0 + kc) = o;
}

// ---------------- Aggregation layer 1: fp32 x[N][128] -> bf16 out[N][128] ----------------
// 4 waves/block, one wave per node; lane handles 2 feats (float2 = 8B/lane).

__global__ __launch_bounds__(256) void aggregate1_kernel(
    const float* __restrict__ x, const int* __restrict__ adj,
    const unsigned* __restrict__ rowptr, const float* __restrict__ eps_arr,
    bf16_t* __restrict__ out)
{
    int w = threadIdx.x >> 6, lane = threadIdx.x & 63;
    int n = blockIdx.x * 4 + w;
    if (n >= N_NODES) return;
    unsigned beg = rowptr[n], end = rowptr[n + 1];
    float a0 = 0.f, a1 = 0.f;
    unsigned e = beg;
    for (; e + 1 < end; e += 2) {
        int s0 = adj[e], s1 = adj[e + 1];
        float2 v0 = *reinterpret_cast<const float2*>(x + (size_t)s0 * N_FEAT + lane * 2);
        float2 v1 = *reinterpret_cast<const float2*>(x + (size_t)s1 * N_FEAT + lane * 2);
        a0 += v0.x + v1.x; a1 += v0.y + v1.y;
    }
    if (e < end) {
        float2 v0 = *reinterpret_cast<const float2*>(x + (size_t)adj[e] * N_FEAT + lane * 2);
        a0 += v0.x; a1 += v0.y;
    }
    float2 self = *reinterpret_cast<const float2*>(x + (size_t)n * N_FEAT + lane * 2);
    float ep = 1.f + eps_arr[0];
    a0 += ep * self.x; a1 += ep * self.y;
    bf16_t* o = out + (size_t)n * N_FEAT + lane * 2;
    o[0] = __float2bfloat16(a0);
    o[1] = __float2bfloat16(a1);
}

// ---------------- Aggregation layers 2-4: bf16 [N][256] -> bf16 [N][256] ----------------
// lane handles 4 feats (short4 = 8B/lane), fp32 accumulate.

__global__ __launch_bounds__(256) void aggregate2_kernel(
    const bf16_t* __restrict__ x, const int* __restrict__ adj,
    const unsigned* __restrict__ rowptr, const float* __restrict__ eps_arr, int eps_idx,
    bf16_t* __restrict__ out)
{
    int w = threadIdx.x >> 6, lane = threadIdx.x & 63;
    int n = blockIdx.x * 4 + w;
    if (n >= N_NODES) return;
    unsigned beg = rowptr[n], end = rowptr[n + 1];
    float a0 = 0.f, a1 = 0.f, a2 = 0.f, a3 = 0.f;
    const short* xs = (const short*)x;
    unsigned e = beg;
    for (; e + 1 < end; e += 2) {
        int s0 = adj[e], s1 = adj[e + 1];
        short4 v0 = *reinterpret_cast<const short4*>(xs + (size_t)s0 * HIDDEN + lane * 4);
        short4 v1 = *reinterpret_cast<const short4*>(xs + (size_t)s1 * HIDDEN + lane * 4);
        a0 += bfb2f(v0.x) + bfb2f(v1.x);
        a1 += bfb2f(v0.y) + bfb2f(v1.y);
        a2 += bfb2f(v0.z) + bfb2f(v1.z);
        a3 += bfb2f(v0.w) + bfb2f(v1.w);
    }
    if (e < end) {
        short4 v0 = *reinterpret_cast<const short4*>(xs + (size_t)adj[e] * HIDDEN + lane * 4);
        a0 += bfb2f(v0.x); a1 += bfb2f(v0.y); a2 += bfb2f(v0.z); a3 += bfb2f(v0.w);
    }
    short4 sv = *reinterpret_cast<const short4*>(xs + (size_t)n * HIDDEN + lane * 4);
    float ep = 1.f + eps_arr[eps_idx];
    a0 += ep * bfb2f(sv.x); a1 += ep * bfb2f(sv.y);
    a2 += ep * bfb2f(sv.z); a3 += ep * bfb2f(sv.w);
    short4 o;
    o.x = f2bfb(a0); o.y = f2bfb(a1); o.z = f2bfb(a2); o.w = f2bfb(a3);
    *reinterpret_cast<short4*>((short*)out + (size_t)n * HIDDEN + lane * 4) = o;
}

// ---------------- bf16 MFMA GEMM: C[M][256] = act(A[M][K] @ W) ----------------
// A bf16 [M][K]; Wt bf16 [256][K] (pre-transposed). 64x64 tile, 4 waves 2x2,
// BK=32 (one mfma_16x16x32 per frag pair per k-step). Epilogue via LDS bounce.

#define GBM 64
#define GBN 64

__global__ __launch_bounds__(256) void gemm_bf16_kernel(
    const bf16_t* __restrict__ A, const bf16_t* __restrict__ Wt,
    const float* __restrict__ bias, bf16_t* __restrict__ C,
    int M, int K,
    const float* __restrict__ bn_g, const float* __restrict__ bn_b,
    const float* __restrict__ bn_m, const float* __restrict__ bn_v, int do_bn)
{
    __shared__ short As[GBM][40];   // +8 pad: row stride 80B -> 2-way bank alias (free)
    __shared__ short Bs[GBN][40];
    __shared__ short Cs[GBM][72];   // +8 pad: row stride 144B

    int tid = threadIdx.x;
    int lane = tid & 63;
    int wave = tid >> 6;
    int wr = wave >> 1, wc = wave & 1;
    int row0 = blockIdx.x * GBM, col0 = blockIdx.y * GBN;

    int lr = tid >> 2, lc = tid & 3;   // tile loads: row 0..63, 16B chunk 0..3

    const short* Ab = (const short*)A;
    const short* Wb = (const short*)Wt;

    f32x4 acc[2][2] = {};

    for (int k0 = 0; k0 < K; k0 += 32) {
        bf16x8 av = {};
        int arow = row0 + lr;
        if (arow < M)
            av = *reinterpret_cast<const bf16x8*>(Ab + (size_t)arow * K + k0 + lc * 8);
        *reinterpret_cast<bf16x8*>(&As[lr][lc * 8]) = av;
        bf16x8 bv = *reinterpret_cast<const bf16x8*>(Wb + (size_t)(col0 + lr) * K + k0 + lc * 8);
        *reinterpret_cast<bf16x8*>(&Bs[lr][lc * 8]) = bv;
        __syncthreads();

        int fr = lane & 15, fk = (lane >> 4) * 8;
        bf16x8 a0 = *reinterpret_cast<const bf16x8*>(&As[wr * 32 + fr][fk]);
        bf16x8 a1 = *reinterpret_cast<const bf16x8*>(&As[wr * 32 + 16 + fr][fk]);
        bf16x8 b0 = *reinterpret_cast<const bf16x8*>(&Bs[wc * 32 + fr][fk]);
        bf16x8 b1 = *reinterpret_cast<const bf16x8*>(&Bs[wc * 32 + 16 + fr][fk]);
        acc[0][0] = __builtin_amdgcn_mfma_f32_16x16x32_bf16(a0, b0, acc[0][0], 0, 0, 0);
        acc[0][1] = __builtin_amdgcn_mfma_f32_16x16x32_bf16(a0, b1, acc[0][1], 0, 0, 0);
        acc[1][0] = __builtin_amdgcn_mfma_f32_16x16x32_bf16(a1, b0, acc[1][0], 0, 0, 0);
        acc[1][1] = __builtin_amdgcn_mfma_f32_16x16x32_bf16(a1, b1, acc[1][1], 0, 0, 0);
        __syncthreads();
    }

    // epilogue: bias + relu (+ BN), bf16 convert, bounce via LDS for coalesced stores
    #pragma unroll
    for (int m = 0; m < 2; m++) {
        #pragma unroll
        for (int n = 0; n < 2; n++) {
            int rl = wr * 32 + m * 16 + (lane >> 4) * 4;
            int cl = wc * 32 + n * 16 + (lane & 15);
            int c = col0 + cl;
            float bi = bias[c];
            #pragma unroll
            for (int r = 0; r < 4; r++) {
                float v = acc[m][n][r] + bi;
                v = fmaxf(v, 0.f);
                if (do_bn) v = (v - bn_m[c]) * rsqrtf(bn_v[c] + 1e-5f) * bn_g[c] + bn_b[c];
                Cs[rl + r][cl] = f2bfb(v);
            }
        }
    }
    __syncthreads();
    int r = row0 + lr;
    if (r < M) {
        bf16x8 c0 = *reinterpret_cast<const bf16x8*>(&Cs[lr][lc * 16]);
        bf16x8 c1 = *reinterpret_cast<const bf16x8*>(&Cs[lr][lc * 16 + 8]);
        short* Cb = (short*)C;
        *reinterpret_cast<bf16x8*>(Cb + (size_t)r * HIDDEN + col0 + lc * 16) = c0;
        *reinterpret_cast<bf16x8*>(Cb + (size_t)r * HIDDEN + col0 + lc * 16 + 8) = c1;
    }
}

// ---------------- Pool: per-graph mean over sorted batch ids (bf16 in, fp32 out) ----------------

__global__ void pool_kernel(const bf16_t* __restrict__ h, const int* __restrict__ batch,
                            float* __restrict__ pooled) {
    int g = blockIdx.x;
    __shared__ int sbeg, send;
    if (threadIdx.x == 0) {
        int lo = 0, hi = N_NODES;
        while (lo < hi) { int mid = (lo + hi) >> 1; if (batch[mid] < g) lo = mid + 1; else hi = mid; }
        sbeg = lo;
        hi = N_NODES;
        while (lo < hi) { int mid = (lo + hi) >> 1; if (batch[mid] < g + 1) lo = mid + 1; else hi = mid; }
        send = lo;
    }
    __syncthreads();
    int t = threadIdx.x;
    float s = 0.f;
    const short* hb = (const short*)h;
    for (int n = sbeg; n < send; n++) s += bfb2f(hb[(size_t)n * HIDDEN + t]);
    float cnt = (float)(send - sbeg);
    pooled[g * HIDDEN + t] = s / fmaxf(cnt, 1.f);
}

// ---------------- Head ----------------

__global__ void head_kernel(const float* __restrict__ pooled,
                            const float* __restrict__ w1, const float* __restrict__ b1,
                            const float* __restrict__ w2, const float* __restrict__ b2,
                            float* __restrict__ out) {
    int g = blockIdx.x, t = threadIdx.x;
    __shared__ float p[HIDDEN];
    __shared__ float h1[HIDDEN];
    __shared__ float lg[N_CLASSES];
    p[t] = pooled[g * HIDDEN + t];
    __syncthreads();
    float acc = b1[t];
    for (int k = 0; k < HIDDEN; k++) acc += p[k] * w1[k * HIDDEN + t];
    h1[t] = fmaxf(acc, 0.f);
    __syncthreads();
    if (t < N_CLASSES) {
        float a = b2[t];
        for (int k = 0; k < HIDDEN; k++) a += h1[k] * w2[k * N_CLASSES + t];
        lg[t] = a;
    }
    __syncthreads();
    if (t == 0) {
        float mx = lg[0];
        for (int j = 1; j < N_CLASSES; j++) mx = fmaxf(mx, lg[j]);
        float se = 0.f;
        for (int j = 0; j < N_CLASSES; j++) se += expf(lg[j] - mx);
        float lse = mx + logf(se);
        for (int j = 0; j < N_CLASSES; j++) out[g * N_CLASSES + j] = lg[j] - lse;
    }
}

// ---------------- Launch ----------------

extern "C" void kernel_launch(void* const* d_in, const int* in_sizes, int n_in,
                              void* d_out, int out_size, void* d_ws, size_t ws_size,
                              hipStream_t stream) {
    const float* x       = (const float*)d_in[0];
    const int*   ei      = (const int*)d_in[1];     // int32 on device (harness contract)
    const int*   batch   = (const int*)d_in[2];
    const float* c1_w0   = (const float*)d_in[3];
    const float* c1_b0   = (const float*)d_in[4];
    const float* c1_w1   = (const float*)d_in[5];
    const float* c1_b1   = (const float*)d_in[6];
    const float* c1_g    = (const float*)d_in[7];
    const float* c1_be   = (const float*)d_in[8];
    const float* c1_m    = (const float*)d_in[9];
    const float* c1_v    = (const float*)d_in[10];
    const float* cs_w0   = (const float*)d_in[11];
    const float* cs_b0   = (const float*)d_in[12];
    const float* cs_w1   = (const float*)d_in[13];
    const float* cs_b1   = (const float*)d_in[14];
    const float* cs_g    = (const float*)d_in[15];
    const float* cs_be   = (const float*)d_in[16];
    const float* cs_m    = (const float*)d_in[17];
    const float* cs_v    = (const float*)d_in[18];
    const float* eps     = (const float*)d_in[19];
    const float* lin1_w  = (const float*)d_in[20];
    const float* lin1_b  = (const float*)d_in[21];
    const float* lin2_w  = (const float*)d_in[22];
    const float* lin2_b  = (const float*)d_in[23];

    char* ws = (char*)d_ws;
    size_t off = 0;
    auto alloc = [&](size_t bytes) -> void* {
        void* p = ws + off;
        off += (bytes + 255) & ~(size_t)255;
        return p;
    };

    unsigned* deg    = (unsigned*)alloc(N_NODES * 4);
    unsigned* rowptr = (unsigned*)alloc((N_NODES + 1) * 4);
    unsigned* cursor = (unsigned*)alloc(N_NODES * 4);
    int*      adj    = (int*)alloc(N_EDGES * 4);
    bf16_t*   Wt     = (bf16_t*)alloc((size_t)(32768 + 7 * 65536) * 2);
    bf16_t*   B1     = (bf16_t*)alloc((size_t)N_NODES * HIDDEN * 2);
    bf16_t*   B2     = (bf16_t*)alloc((size_t)N_NODES * HIDDEN * 2);
    bf16_t*   B3     = (bf16_t*)alloc((size_t)N_NODES * HIDDEN * 2);
    float*    pooled = (float*)alloc(N_GRAPHS * HIDDEN * 4);

    // transposed weight pointers (element offsets into Wt)
    bf16_t* wt_10 = Wt;                       // c1_w0^T  [256][128]
    bf16_t* wt_11 = Wt + 32768;               // c1_w1^T  [256][256]
    auto wt_c0 = [&](int i) { return Wt + 32768 + (size_t)(1 + 2 * i) * 65536; };
    auto wt_c1 = [&](int i) { return Wt + 32768 + (size_t)(2 + 2 * i) * 65536; };

    hipMemsetAsync(deg, 0, N_NODES * 4, stream);

    int eb = (N_EDGES + 255) / 256;
    count_deg_kernel<<<eb, 256, 0, stream>>>(ei, deg);
    scan_kernel<<<1, 1024, 0, stream>>>(deg, rowptr);
    init_cursor_kernel<<<(N_NODES + 255) / 256, 256, 0, stream>>>(rowptr, cursor);
    fill_adj_kernel<<<eb, 256, 0, stream>>>(ei, cursor, adj);

    prep_weights_kernel<<<dim3(8, 8, 8), 256, 0, stream>>>(c1_w0, c1_w1, cs_w0, cs_w1, Wt);

    dim3 ggrid((N_NODES + GBM - 1) / GBM, HIDDEN / GBN);
    int ab = (N_NODES + 3) / 4;

    // Layer 1 (F=128)
    aggregate1_kernel<<<ab, 256, 0, stream>>>(x, adj, rowptr, eps, B1);
    gemm_bf16_kernel<<<ggrid, 256, 0, stream>>>(B1, wt_10, c1_b0, B2, N_NODES, N_FEAT,
                                                nullptr, nullptr, nullptr, nullptr, 0);
    gemm_bf16_kernel<<<ggrid, 256, 0, stream>>>(B2, wt_11, c1_b1, B3, N_NODES, HIDDEN,
                                                c1_g, c1_be, c1_m, c1_v, 1);

    // Layers 2..4 (F=256)
    for (int i = 0; i < 3; i++) {
        aggregate2_kernel<<<ab, 256, 0, stream>>>(B3, adj, rowptr, eps, i + 1, B1);
        gemm_bf16_kernel<<<ggrid, 256, 0, stream>>>(B1, wt_c0(i), cs_b0 + i * HIDDEN, B2,
                                                    N_NODES, HIDDEN,
                                                    nullptr, nullptr, nullptr, nullptr, 0);
        gemm_bf16_kernel<<<ggrid, 256, 0, stream>>>(B2, wt_c1(i), cs_b1 + i * HIDDEN, B3,
                                                    N_NODES, HIDDEN,
                                                    cs_g + i * HIDDEN, cs_be + i * HIDDEN,
                                                    cs_m + i * HIDDEN, cs_v + i * HIDDEN, 1);
    }

    pool_kernel<<<N_GRAPHS, HIDDEN, 0, stream>>>(B3, batch, pooled);
    head_kernel<<<N_GRAPHS, HIDDEN, 0, stream>>>(pooled, lin1_w, lin1_b, lin2_w, lin2_b, (float*)d_out);
}

// Round 4
// 613.413 us; speedup vs baseline: 2.6050x; 1.1603x over previous
//
#include <hip/hip_runtime.h>
#include <hip/hip_bf16.h>

#define N_NODES 50000
#define N_EDGES 800000
#define N_FEAT 128
#define HIDDEN 256
#define N_GRAPHS 256
#define N_CLASSES 10
#define SCAN_NB ((N_NODES + 255) / 256)   // 196 scan blocks

typedef __hip_bfloat16 bf16_t;
typedef short bf16x8 __attribute__((ext_vector_type(8)));
typedef float f32x4 __attribute__((ext_vector_type(4)));

__device__ inline float bfb2f(short s) {
    unsigned u = ((unsigned)(unsigned short)s) << 16;
    float f; __builtin_memcpy(&f, &u, 4); return f;
}
__device__ inline short f2bfb(float f) {
    bf16_t b = __float2bfloat16(f);
    short s; __builtin_memcpy(&s, &b, 2); return s;
}

// ---------------- CSR build ----------------

__global__ void count_deg_kernel(const int* __restrict__ ei, unsigned* __restrict__ deg) {
    int e = blockIdx.x * blockDim.x + threadIdx.x;
    if (e < N_EDGES) atomicAdd(&deg[ei[N_EDGES + e]], 1u);
}

// parallel exclusive scan, 3 phases
__global__ __launch_bounds__(256) void scan_a_kernel(const unsigned* __restrict__ deg,
                                                     unsigned* __restrict__ rowptr,
                                                     unsigned* __restrict__ blocksum) {
    __shared__ unsigned tmp[256];
    int t = threadIdx.x;
    int g = blockIdx.x * 256 + t;
    unsigned v = (g < N_NODES) ? deg[g] : 0u;
    tmp[t] = v;
    __syncthreads();
    #pragma unroll
    for (int off = 1; off < 256; off <<= 1) {
        unsigned add = (t >= off) ? tmp[t - off] : 0u;
        __syncthreads();
        tmp[t] += add;
        __syncthreads();
    }
    if (g < N_NODES) rowptr[g] = tmp[t] - v;           // exclusive (pre-offset)
    if (t == 255) blocksum[blockIdx.x] = tmp[t];
}

__global__ __launch_bounds__(256) void scan_b_kernel(unsigned* __restrict__ blocksum) {
    __shared__ unsigned tmp[256];
    int t = threadIdx.x;
    unsigned v = (t < SCAN_NB) ? blocksum[t] : 0u;
    tmp[t] = v;
    __syncthreads();
    #pragma unroll
    for (int off = 1; off < 256; off <<= 1) {
        unsigned add = (t >= off) ? tmp[t - off] : 0u;
        __syncthreads();
        tmp[t] += add;
        __syncthreads();
    }
    if (t < SCAN_NB) blocksum[t] = tmp[t] - v;         // exclusive block offsets
}

__global__ __launch_bounds__(256) void scan_c_kernel(unsigned* __restrict__ rowptr,
                                                     const unsigned* __restrict__ blocksum,
                                                     unsigned* __restrict__ cursor) {
    int g = blockIdx.x * 256 + threadIdx.x;
    if (g < N_NODES) {
        unsigned r = rowptr[g] + blocksum[blockIdx.x];
        rowptr[g] = r;
        cursor[g] = r;
    }
    if (g == 0) rowptr[N_NODES] = N_EDGES;
}

__global__ void fill_adj_kernel(const int* __restrict__ ei, unsigned* __restrict__ cursor,
                                int* __restrict__ adj) {
    int e = blockIdx.x * blockDim.x + threadIdx.x;
    if (e < N_EDGES) {
        int src = ei[e];
        int dst = ei[N_EDGES + e];
        unsigned pos = atomicAdd(&cursor[dst], 1u);
        adj[pos] = src;
    }
}

// ---------------- Weight prep: fp32 W[K][256] -> bf16 Wt[256][K] ----------------

__global__ __launch_bounds__(256) void prep_weights_kernel(
    const float* __restrict__ c1_w0, const float* __restrict__ c1_w1,
    const float* __restrict__ cs_w0, const float* __restrict__ cs_w1,
    bf16_t* __restrict__ wt)
{
    __shared__ float T[32][33];
    int z = blockIdx.z;
    const float* src; int K; size_t off;
    if (z == 0)      { src = c1_w0; K = N_FEAT;  off = 0; }
    else if (z == 1) { src = c1_w1; K = HIDDEN;  off = 32768; }
    else {
        int i = (z - 2) >> 1;
        src = (((z - 2) & 1) ? cs_w1 : cs_w0) + (size_t)i * HIDDEN * HIDDEN;
        K = HIDDEN;
        off = 32768 + (size_t)(z - 1) * 65536;
    }
    int k0 = blockIdx.x * 32, n0 = blockIdx.y * 32;
    if (k0 >= K) return;
    int t = threadIdx.x;
    int r = t >> 3, c4 = (t & 7) * 4;
    float4 v = *reinterpret_cast<const float4*>(src + (size_t)(k0 + r) * HIDDEN + n0 + c4);
    T[r][c4 + 0] = v.x; T[r][c4 + 1] = v.y; T[r][c4 + 2] = v.z; T[r][c4 + 3] = v.w;
    __syncthreads();
    int n = t >> 3, kc = (t & 7) * 4;
    short4 o;
    o.x = f2bfb(T[kc + 0][n]); o.y = f2bfb(T[kc + 1][n]);
    o.z = f2bfb(T[kc + 2][n]); o.w = f2bfb(T[kc + 3][n]);
    *reinterpret_cast<short4*>((short*)wt + off + (size_t)(n0 + n) * K + k0 + kc) = o;
}

// ---------------- Aggregation layer 1: fp32 x[N][128] -> bf16 out[N][128] ----------------
// One wave per node. Half-wave per edge: lanes 0-31 edge e, lanes 32-63 edge e+1,
// 16B/lane (float4). Uniform trip count, combine with shfl_xor(32).

__global__ __launch_bounds__(256) void aggregate1_kernel(
    const float* __restrict__ x, const int* __restrict__ adj,
    const unsigned* __restrict__ rowptr, const float* __restrict__ eps_arr,
    bf16_t* __restrict__ out)
{
    int w = threadIdx.x >> 6, lane = threadIdx.x & 63;
    int n = blockIdx.x * 4 + w;
    if (n >= N_NODES) return;
    int half = lane >> 5, l5 = lane & 31;
    unsigned beg = rowptr[n], end = rowptr[n + 1];
    float a0 = 0.f, a1 = 0.f, a2 = 0.f, a3 = 0.f;
    unsigned e = beg;
    for (; e + 4 <= end; e += 4) {
        int s0 = adj[e + half];
        int s1 = adj[e + 2 + half];
        float4 v0 = *reinterpret_cast<const float4*>(x + (unsigned)s0 * N_FEAT + l5 * 4);
        float4 v1 = *reinterpret_cast<const float4*>(x + (unsigned)s1 * N_FEAT + l5 * 4);
        a0 += v0.x + v1.x; a1 += v0.y + v1.y; a2 += v0.z + v1.z; a3 += v0.w + v1.w;
    }
    for (; e + 2 <= end; e += 2) {
        int s0 = adj[e + half];
        float4 v0 = *reinterpret_cast<const float4*>(x + (unsigned)s0 * N_FEAT + l5 * 4);
        a0 += v0.x; a1 += v0.y; a2 += v0.z; a3 += v0.w;
    }
    if (e < end && half == 0) {
        float4 v0 = *reinterpret_cast<const float4*>(x + (unsigned)adj[e] * N_FEAT + l5 * 4);
        a0 += v0.x; a1 += v0.y; a2 += v0.z; a3 += v0.w;
    }
    if (half == 0) {
        float4 sv = *reinterpret_cast<const float4*>(x + (unsigned)n * N_FEAT + l5 * 4);
        float ep = 1.f + eps_arr[0];
        a0 += ep * sv.x; a1 += ep * sv.y; a2 += ep * sv.z; a3 += ep * sv.w;
    }
    a0 += __shfl_xor(a0, 32);
    a1 += __shfl_xor(a1, 32);
    a2 += __shfl_xor(a2, 32);
    a3 += __shfl_xor(a3, 32);
    if (half == 0) {
        short4 o;
        o.x = f2bfb(a0); o.y = f2bfb(a1); o.z = f2bfb(a2); o.w = f2bfb(a3);
        *reinterpret_cast<short4*>((short*)out + (unsigned)n * N_FEAT + l5 * 4) = o;
    }
}

// ---------------- Aggregation layers 2-4: bf16 [N][256] -> bf16 [N][256] ----------------
// Same half-wave-per-edge structure, 16B/lane (bf16x8), fp32 accumulate.

__global__ __launch_bounds__(256) void aggregate2_kernel(
    const bf16_t* __restrict__ x, const int* __restrict__ adj,
    const unsigned* __restrict__ rowptr, const float* __restrict__ eps_arr, int eps_idx,
    bf16_t* __restrict__ out)
{
    int w = threadIdx.x >> 6, lane = threadIdx.x & 63;
    int n = blockIdx.x * 4 + w;
    if (n >= N_NODES) return;
    int half = lane >> 5, l5 = lane & 31;
    unsigned beg = rowptr[n], end = rowptr[n + 1];
    const short* xs = (const short*)x;
    float acc[8] = {};
    unsigned e = beg;
    for (; e + 4 <= end; e += 4) {
        int s0 = adj[e + half];
        int s1 = adj[e + 2 + half];
        bf16x8 v0 = *reinterpret_cast<const bf16x8*>(xs + (unsigned)s0 * HIDDEN + l5 * 8);
        bf16x8 v1 = *reinterpret_cast<const bf16x8*>(xs + (unsigned)s1 * HIDDEN + l5 * 8);
        #pragma unroll
        for (int j = 0; j < 8; j++) acc[j] += bfb2f(v0[j]) + bfb2f(v1[j]);
    }
    for (; e + 2 <= end; e += 2) {
        int s0 = adj[e + half];
        bf16x8 v0 = *reinterpret_cast<const bf16x8*>(xs + (unsigned)s0 * HIDDEN + l5 * 8);
        #pragma unroll
        for (int j = 0; j < 8; j++) acc[j] += bfb2f(v0[j]);
    }
    if (e < end && half == 0) {
        bf16x8 v0 = *reinterpret_cast<const bf16x8*>(xs + (unsigned)adj[e] * HIDDEN + l5 * 8);
        #pragma unroll
        for (int j = 0; j < 8; j++) acc[j] += bfb2f(v0[j]);
    }
    if (half == 0) {
        bf16x8 sv = *reinterpret_cast<const bf16x8*>(xs + (unsigned)n * HIDDEN + l5 * 8);
        float ep = 1.f + eps_arr[eps_idx];
        #pragma unroll
        for (int j = 0; j < 8; j++) acc[j] += ep * bfb2f(sv[j]);
    }
    #pragma unroll
    for (int j = 0; j < 8; j++) acc[j] += __shfl_xor(acc[j], 32);
    if (half == 0) {
        bf16x8 o;
        #pragma unroll
        for (int j = 0; j < 8; j++) o[j] = f2bfb(acc[j]);
        *reinterpret_cast<bf16x8*>((short*)out + (unsigned)n * HIDDEN + l5 * 8) = o;
    }
}

// ---------------- bf16 MFMA GEMM: C[M][256] = act(A[M][K] @ W) ----------------

#define GBM 64
#define GBN 64

__global__ __launch_bounds__(256) void gemm_bf16_kernel(
    const bf16_t* __restrict__ A, const bf16_t* __restrict__ Wt,
    const float* __restrict__ bias, bf16_t* __restrict__ C,
    int M, int K,
    const float* __restrict__ bn_g, const float* __restrict__ bn_b,
    const float* __restrict__ bn_m, const float* __restrict__ bn_v, int do_bn)
{
    __shared__ short As[GBM][40];
    __shared__ short Bs[GBN][40];
    __shared__ short Cs[GBM][72];

    int tid = threadIdx.x;
    int lane = tid & 63;
    int wave = tid >> 6;
    int wr = wave >> 1, wc = wave & 1;
    int row0 = blockIdx.x * GBM, col0 = blockIdx.y * GBN;

    int lr = tid >> 2, lc = tid & 3;

    const short* Ab = (const short*)A;
    const short* Wb = (const short*)Wt;

    f32x4 acc[2][2] = {};

    for (int k0 = 0; k0 < K; k0 += 32) {
        bf16x8 av = {};
        int arow = row0 + lr;
        if (arow < M)
            av = *reinterpret_cast<const bf16x8*>(Ab + (size_t)arow * K + k0 + lc * 8);
        *reinterpret_cast<bf16x8*>(&As[lr][lc * 8]) = av;
        bf16x8 bv = *reinterpret_cast<const bf16x8*>(Wb + (size_t)(col0 + lr) * K + k0 + lc * 8);
        *reinterpret_cast<bf16x8*>(&Bs[lr][lc * 8]) = bv;
        __syncthreads();

        int fr = lane & 15, fk = (lane >> 4) * 8;
        bf16x8 a0 = *reinterpret_cast<const bf16x8*>(&As[wr * 32 + fr][fk]);
        bf16x8 a1 = *reinterpret_cast<const bf16x8*>(&As[wr * 32 + 16 + fr][fk]);
        bf16x8 b0 = *reinterpret_cast<const bf16x8*>(&Bs[wc * 32 + fr][fk]);
        bf16x8 b1 = *reinterpret_cast<const bf16x8*>(&Bs[wc * 32 + 16 + fr][fk]);
        acc[0][0] = __builtin_amdgcn_mfma_f32_16x16x32_bf16(a0, b0, acc[0][0], 0, 0, 0);
        acc[0][1] = __builtin_amdgcn_mfma_f32_16x16x32_bf16(a0, b1, acc[0][1], 0, 0, 0);
        acc[1][0] = __builtin_amdgcn_mfma_f32_16x16x32_bf16(a1, b0, acc[1][0], 0, 0, 0);
        acc[1][1] = __builtin_amdgcn_mfma_f32_16x16x32_bf16(a1, b1, acc[1][1], 0, 0, 0);
        __syncthreads();
    }

    #pragma unroll
    for (int m = 0; m < 2; m++) {
        #pragma unroll
        for (int n = 0; n < 2; n++) {
            int rl = wr * 32 + m * 16 + (lane >> 4) * 4;
            int cl = wc * 32 + n * 16 + (lane & 15);
            int c = col0 + cl;
            float bi = bias[c];
            #pragma unroll
            for (int r = 0; r < 4; r++) {
                float v = acc[m][n][r] + bi;
                v = fmaxf(v, 0.f);
                if (do_bn) v = (v - bn_m[c]) * rsqrtf(bn_v[c] + 1e-5f) * bn_g[c] + bn_b[c];
                Cs[rl + r][cl] = f2bfb(v);
            }
        }
    }
    __syncthreads();
    int r = row0 + lr;
    if (r < M) {
        bf16x8 c0 = *reinterpret_cast<const bf16x8*>(&Cs[lr][lc * 16]);
        bf16x8 c1 = *reinterpret_cast<const bf16x8*>(&Cs[lr][lc * 16 + 8]);
        short* Cb = (short*)C;
        *reinterpret_cast<bf16x8*>(Cb + (size_t)r * HIDDEN + col0 + lc * 16) = c0;
        *reinterpret_cast<bf16x8*>(Cb + (size_t)r * HIDDEN + col0 + lc * 16 + 8) = c1;
    }
}

// ---------------- Pool ----------------

__global__ void pool_kernel(const bf16_t* __restrict__ h, const int* __restrict__ batch,
                            float* __restrict__ pooled) {
    int g = blockIdx.x;
    __shared__ int sbeg, send;
    if (threadIdx.x == 0) {
        int lo = 0, hi = N_NODES;
        while (lo < hi) { int mid = (lo + hi) >> 1; if (batch[mid] < g) lo = mid + 1; else hi = mid; }
        sbeg = lo;
        hi = N_NODES;
        while (lo < hi) { int mid = (lo + hi) >> 1; if (batch[mid] < g + 1) lo = mid + 1; else hi = mid; }
        send = lo;
    }
    __syncthreads();
    int t = threadIdx.x;
    float s = 0.f;
    const short* hb = (const short*)h;
    for (int n = sbeg; n < send; n++) s += bfb2f(hb[(size_t)n * HIDDEN + t]);
    float cnt = (float)(send - sbeg);
    pooled[g * HIDDEN + t] = s / fmaxf(cnt, 1.f);
}

// ---------------- Head ----------------

__global__ void head_kernel(const float* __restrict__ pooled,
                            const float* __restrict__ w1, const float* __restrict__ b1,
                            const float* __restrict__ w2, const float* __restrict__ b2,
                            float* __restrict__ out) {
    int g = blockIdx.x, t = threadIdx.x;
    __shared__ float p[HIDDEN];
    __shared__ float h1[HIDDEN];
    __shared__ float lg[N_CLASSES];
    p[t] = pooled[g * HIDDEN + t];
    __syncthreads();
    float acc = b1[t];
    for (int k = 0; k < HIDDEN; k++) acc += p[k] * w1[k * HIDDEN + t];
    h1[t] = fmaxf(acc, 0.f);
    __syncthreads();
    if (t < N_CLASSES) {
        float a = b2[t];
        for (int k = 0; k < HIDDEN; k++) a += h1[k] * w2[k * N_CLASSES + t];
        lg[t] = a;
    }
    __syncthreads();
    if (t == 0) {
        float mx = lg[0];
        for (int j = 1; j < N_CLASSES; j++) mx = fmaxf(mx, lg[j]);
        float se = 0.f;
        for (int j = 0; j < N_CLASSES; j++) se += expf(lg[j] - mx);
        float lse = mx + logf(se);
        for (int j = 0; j < N_CLASSES; j++) out[g * N_CLASSES + j] = lg[j] - lse;
    }
}

// ---------------- Launch ----------------

extern "C" void kernel_launch(void* const* d_in, const int* in_sizes, int n_in,
                              void* d_out, int out_size, void* d_ws, size_t ws_size,
                              hipStream_t stream) {
    const float* x       = (const float*)d_in[0];
    const int*   ei      = (const int*)d_in[1];     // int32 on device (harness contract)
    const int*   batch   = (const int*)d_in[2];
    const float* c1_w0   = (const float*)d_in[3];
    const float* c1_b0   = (const float*)d_in[4];
    const float* c1_w1   = (const float*)d_in[5];
    const float* c1_b1   = (const float*)d_in[6];
    const float* c1_g    = (const float*)d_in[7];
    const float* c1_be   = (const float*)d_in[8];
    const float* c1_m    = (const float*)d_in[9];
    const float* c1_v    = (const float*)d_in[10];
    const float* cs_w0   = (const float*)d_in[11];
    const float* cs_b0   = (const float*)d_in[12];
    const float* cs_w1   = (const float*)d_in[13];
    const float* cs_b1   = (const float*)d_in[14];
    const float* cs_g    = (const float*)d_in[15];
    const float* cs_be   = (const float*)d_in[16];
    const float* cs_m    = (const float*)d_in[17];
    const float* cs_v    = (const float*)d_in[18];
    const float* eps     = (const float*)d_in[19];
    const float* lin1_w  = (const float*)d_in[20];
    const float* lin1_b  = (const float*)d_in[21];
    const float* lin2_w  = (const float*)d_in[22];
    const float* lin2_b  = (const float*)d_in[23];

    char* ws = (char*)d_ws;
    size_t off = 0;
    auto alloc = [&](size_t bytes) -> void* {
        void* p = ws + off;
        off += (bytes + 255) & ~(size_t)255;
        return p;
    };

    unsigned* deg      = (unsigned*)alloc(N_NODES * 4);
    unsigned* rowptr   = (unsigned*)alloc((N_NODES + 1) * 4);
    unsigned* cursor   = (unsigned*)alloc(N_NODES * 4);
    unsigned* blocksum = (unsigned*)alloc(SCAN_NB * 4);
    int*      adj      = (int*)alloc(N_EDGES * 4);
    bf16_t*   Wt       = (bf16_t*)alloc((size_t)(32768 + 7 * 65536) * 2);
    bf16_t*   B1       = (bf16_t*)alloc((size_t)N_NODES * HIDDEN * 2);
    bf16_t*   B2       = (bf16_t*)alloc((size_t)N_NODES * HIDDEN * 2);
    bf16_t*   B3       = (bf16_t*)alloc((size_t)N_NODES * HIDDEN * 2);
    float*    pooled   = (float*)alloc(N_GRAPHS * HIDDEN * 4);

    bf16_t* wt_10 = Wt;                       // c1_w0^T  [256][128]
    bf16_t* wt_11 = Wt + 32768;               // c1_w1^T  [256][256]
    auto wt_c0 = [&](int i) { return Wt + 32768 + (size_t)(1 + 2 * i) * 65536; };
    auto wt_c1 = [&](int i) { return Wt + 32768 + (size_t)(2 + 2 * i) * 65536; };

    hipMemsetAsync(deg, 0, N_NODES * 4, stream);

    int eb = (N_EDGES + 255) / 256;
    count_deg_kernel<<<eb, 256, 0, stream>>>(ei, deg);
    scan_a_kernel<<<SCAN_NB, 256, 0, stream>>>(deg, rowptr, blocksum);
    scan_b_kernel<<<1, 256, 0, stream>>>(blocksum);
    scan_c_kernel<<<SCAN_NB, 256, 0, stream>>>(rowptr, blocksum, cursor);
    fill_adj_kernel<<<eb, 256, 0, stream>>>(ei, cursor, adj);

    prep_weights_kernel<<<dim3(8, 8, 8), 256, 0, stream>>>(c1_w0, c1_w1, cs_w0, cs_w1, Wt);

    dim3 ggrid((N_NODES + GBM - 1) / GBM, HIDDEN / GBN);
    int ab = (N_NODES + 3) / 4;

    // Layer 1 (F=128)
    aggregate1_kernel<<<ab, 256, 0, stream>>>(x, adj, rowptr, eps, B1);
    gemm_bf16_kernel<<<ggrid, 256, 0, stream>>>(B1, wt_10, c1_b0, B2, N_NODES, N_FEAT,
                                                nullptr, nullptr, nullptr, nullptr, 0);
    gemm_bf16_kernel<<<ggrid, 256, 0, stream>>>(B2, wt_11, c1_b1, B3, N_NODES, HIDDEN,
                                                c1_g, c1_be, c1_m, c1_v, 1);

    // Layers 2..4 (F=256)
    for (int i = 0; i < 3; i++) {
        aggregate2_kernel<<<ab, 256, 0, stream>>>(B3, adj, rowptr, eps, i + 1, B1);
        gemm_bf16_kernel<<<ggrid, 256, 0, stream>>>(B1, wt_c0(i), cs_b0 + i * HIDDEN, B2,
                                                    N_NODES, HIDDEN,
                                                    nullptr, nullptr, nullptr, nullptr, 0);
        gemm_bf16_kernel<<<ggrid, 256, 0, stream>>>(B2, wt_c1(i), cs_b1 + i * HIDDEN, B3,
                                                    N_NODES, HIDDEN,
                                                    cs_g + i * HIDDEN, cs_be + i * HIDDEN,
                                                    cs_m + i * HIDDEN, cs_v + i * HIDDEN, 1);
    }

    pool_kernel<<<N_GRAPHS, HIDDEN, 0, stream>>>(B3, batch, pooled);
    head_kernel<<<N_GRAPHS, HIDDEN, 0, stream>>>(pooled, lin1_w, lin1_b, lin2_w, lin2_b, (float*)d_out);
}

// Round 5
// 571.702 us; speedup vs baseline: 2.7951x; 1.0730x over previous
//
#include <hip/hip_runtime.h>
#include <hip/hip_bf16.h>

#define N_NODES 50000
#define N_EDGES 800000
#define N_FEAT 128
#define HIDDEN 256
#define N_GRAPHS 256
#define N_CLASSES 10
#define SCAN_NB ((N_NODES + 255) / 256)   // 196 scan blocks

typedef __hip_bfloat16 bf16_t;
typedef short bf16x8 __attribute__((ext_vector_type(8)));
typedef float f32x4 __attribute__((ext_vector_type(4)));

__device__ inline float bfb2f(short s) {
    unsigned u = ((unsigned)(unsigned short)s) << 16;
    float f; __builtin_memcpy(&f, &u, 4); return f;
}
__device__ inline short f2bfb(float f) {
    bf16_t b = __float2bfloat16(f);
    short s; __builtin_memcpy(&s, &b, 2); return s;
}

// ---------------- CSR build ----------------

__global__ void count_deg_kernel(const int* __restrict__ ei, unsigned* __restrict__ deg) {
    int e = blockIdx.x * blockDim.x + threadIdx.x;
    if (e < N_EDGES) atomicAdd(&deg[ei[N_EDGES + e]], 1u);
}

__global__ __launch_bounds__(256) void scan_a_kernel(const unsigned* __restrict__ deg,
                                                     unsigned* __restrict__ rowptr,
                                                     unsigned* __restrict__ blocksum) {
    __shared__ unsigned tmp[256];
    int t = threadIdx.x;
    int g = blockIdx.x * 256 + t;
    unsigned v = (g < N_NODES) ? deg[g] : 0u;
    tmp[t] = v;
    __syncthreads();
    #pragma unroll
    for (int off = 1; off < 256; off <<= 1) {
        unsigned add = (t >= off) ? tmp[t - off] : 0u;
        __syncthreads();
        tmp[t] += add;
        __syncthreads();
    }
    if (g < N_NODES) rowptr[g] = tmp[t] - v;           // exclusive (pre-offset)
    if (t == 255) blocksum[blockIdx.x] = tmp[t];
}

__global__ __launch_bounds__(256) void scan_b_kernel(unsigned* __restrict__ blocksum) {
    __shared__ unsigned tmp[256];
    int t = threadIdx.x;
    unsigned v = (t < SCAN_NB) ? blocksum[t] : 0u;
    tmp[t] = v;
    __syncthreads();
    #pragma unroll
    for (int off = 1; off < 256; off <<= 1) {
        unsigned add = (t >= off) ? tmp[t - off] : 0u;
        __syncthreads();
        tmp[t] += add;
        __syncthreads();
    }
    if (t < SCAN_NB) blocksum[t] = tmp[t] - v;         // exclusive block offsets
}

__global__ __launch_bounds__(256) void scan_c_kernel(unsigned* __restrict__ rowptr,
                                                     const unsigned* __restrict__ blocksum,
                                                     unsigned* __restrict__ cursor) {
    int g = blockIdx.x * 256 + threadIdx.x;
    if (g < N_NODES) {
        unsigned r = rowptr[g] + blocksum[blockIdx.x];
        rowptr[g] = r;
        cursor[g] = r;
    }
    if (g == 0) rowptr[N_NODES] = N_EDGES;
}

__global__ void fill_adj_kernel(const int* __restrict__ ei, unsigned* __restrict__ cursor,
                                int* __restrict__ adj) {
    int e = blockIdx.x * blockDim.x + threadIdx.x;
    if (e < N_EDGES) {
        int src = ei[e];
        int dst = ei[N_EDGES + e];
        unsigned pos = atomicAdd(&cursor[dst], 1u);
        adj[pos] = src;
    }
}

// ---------------- Weight prep: fp32 W[K][256] -> bf16 Wt[256][K] ----------------

__global__ __launch_bounds__(256) void prep_weights_kernel(
    const float* __restrict__ c1_w0, const float* __restrict__ c1_w1,
    const float* __restrict__ cs_w0, const float* __restrict__ cs_w1,
    bf16_t* __restrict__ wt)
{
    __shared__ float T[32][33];
    int z = blockIdx.z;
    const float* src; int K; size_t off;
    if (z == 0)      { src = c1_w0; K = N_FEAT;  off = 0; }
    else if (z == 1) { src = c1_w1; K = HIDDEN;  off = 32768; }
    else {
        int i = (z - 2) >> 1;
        src = (((z - 2) & 1) ? cs_w1 : cs_w0) + (size_t)i * HIDDEN * HIDDEN;
        K = HIDDEN;
        off = 32768 + (size_t)(z - 1) * 65536;
    }
    int k0 = blockIdx.x * 32, n0 = blockIdx.y * 32;
    if (k0 >= K) return;
    int t = threadIdx.x;
    int r = t >> 3, c4 = (t & 7) * 4;
    float4 v = *reinterpret_cast<const float4*>(src + (size_t)(k0 + r) * HIDDEN + n0 + c4);
    T[r][c4 + 0] = v.x; T[r][c4 + 1] = v.y; T[r][c4 + 2] = v.z; T[r][c4 + 3] = v.w;
    __syncthreads();
    int n = t >> 3, kc = (t & 7) * 4;
    short4 o;
    o.x = f2bfb(T[kc + 0][n]); o.y = f2bfb(T[kc + 1][n]);
    o.z = f2bfb(T[kc + 2][n]); o.w = f2bfb(T[kc + 3][n]);
    *reinterpret_cast<short4*>((short*)wt + off + (size_t)(n0 + n) * K + k0 + kc) = o;
}

// ---------------- Aggregation layer 1: fp32 x[N][128] -> bf16 out[N][128] ----------------

__global__ __launch_bounds__(256) void aggregate1_kernel(
    const float* __restrict__ x, const int* __restrict__ adj,
    const unsigned* __restrict__ rowptr, const float* __restrict__ eps_arr,
    bf16_t* __restrict__ out)
{
    int w = threadIdx.x >> 6, lane = threadIdx.x & 63;
    int n = blockIdx.x * 4 + w;
    if (n >= N_NODES) return;
    int half = lane >> 5, l5 = lane & 31;
    unsigned beg = rowptr[n], end = rowptr[n + 1];
    float a0 = 0.f, a1 = 0.f, a2 = 0.f, a3 = 0.f;
    unsigned e = beg;
    for (; e + 4 <= end; e += 4) {
        int s0 = adj[e + half];
        int s1 = adj[e + 2 + half];
        float4 v0 = *reinterpret_cast<const float4*>(x + (unsigned)s0 * N_FEAT + l5 * 4);
        float4 v1 = *reinterpret_cast<const float4*>(x + (unsigned)s1 * N_FEAT + l5 * 4);
        a0 += v0.x + v1.x; a1 += v0.y + v1.y; a2 += v0.z + v1.z; a3 += v0.w + v1.w;
    }
    for (; e + 2 <= end; e += 2) {
        int s0 = adj[e + half];
        float4 v0 = *reinterpret_cast<const float4*>(x + (unsigned)s0 * N_FEAT + l5 * 4);
        a0 += v0.x; a1 += v0.y; a2 += v0.z; a3 += v0.w;
    }
    if (e < end && half == 0) {
        float4 v0 = *reinterpret_cast<const float4*>(x + (unsigned)adj[e] * N_FEAT + l5 * 4);
        a0 += v0.x; a1 += v0.y; a2 += v0.z; a3 += v0.w;
    }
    if (half == 0) {
        float4 sv = *reinterpret_cast<const float4*>(x + (unsigned)n * N_FEAT + l5 * 4);
        float ep = 1.f + eps_arr[0];
        a0 += ep * sv.x; a1 += ep * sv.y; a2 += ep * sv.z; a3 += ep * sv.w;
    }
    a0 += __shfl_xor(a0, 32);
    a1 += __shfl_xor(a1, 32);
    a2 += __shfl_xor(a2, 32);
    a3 += __shfl_xor(a3, 32);
    if (half == 0) {
        short4 o;
        o.x = f2bfb(a0); o.y = f2bfb(a1); o.z = f2bfb(a2); o.w = f2bfb(a3);
        *reinterpret_cast<short4*>((short*)out + (unsigned)n * N_FEAT + l5 * 4) = o;
    }
}

// ---------------- Aggregation layers 2-4: bf16 [N][256] -> bf16 [N][256] ----------------

__global__ __launch_bounds__(256) void aggregate2_kernel(
    const bf16_t* __restrict__ x, const int* __restrict__ adj,
    const unsigned* __restrict__ rowptr, const float* __restrict__ eps_arr, int eps_idx,
    bf16_t* __restrict__ out)
{
    int w = threadIdx.x >> 6, lane = threadIdx.x & 63;
    int n = blockIdx.x * 4 + w;
    if (n >= N_NODES) return;
    int half = lane >> 5, l5 = lane & 31;
    unsigned beg = rowptr[n], end = rowptr[n + 1];
    const short* xs = (const short*)x;
    float acc[8] = {};
    unsigned e = beg;
    for (; e + 4 <= end; e += 4) {
        int s0 = adj[e + half];
        int s1 = adj[e + 2 + half];
        bf16x8 v0 = *reinterpret_cast<const bf16x8*>(xs + (unsigned)s0 * HIDDEN + l5 * 8);
        bf16x8 v1 = *reinterpret_cast<const bf16x8*>(xs + (unsigned)s1 * HIDDEN + l5 * 8);
        #pragma unroll
        for (int j = 0; j < 8; j++) acc[j] += bfb2f(v0[j]) + bfb2f(v1[j]);
    }
    for (; e + 2 <= end; e += 2) {
        int s0 = adj[e + half];
        bf16x8 v0 = *reinterpret_cast<const bf16x8*>(xs + (unsigned)s0 * HIDDEN + l5 * 8);
        #pragma unroll
        for (int j = 0; j < 8; j++) acc[j] += bfb2f(v0[j]);
    }
    if (e < end && half == 0) {
        bf16x8 v0 = *reinterpret_cast<const bf16x8*>(xs + (unsigned)adj[e] * HIDDEN + l5 * 8);
        #pragma unroll
        for (int j = 0; j < 8; j++) acc[j] += bfb2f(v0[j]);
    }
    if (half == 0) {
        bf16x8 sv = *reinterpret_cast<const bf16x8*>(xs + (unsigned)n * HIDDEN + l5 * 8);
        float ep = 1.f + eps_arr[eps_idx];
        #pragma unroll
        for (int j = 0; j < 8; j++) acc[j] += ep * bfb2f(sv[j]);
    }
    #pragma unroll
    for (int j = 0; j < 8; j++) acc[j] += __shfl_xor(acc[j], 32);
    if (half == 0) {
        bf16x8 o;
        #pragma unroll
        for (int j = 0; j < 8; j++) o[j] = f2bfb(acc[j]);
        *reinterpret_cast<bf16x8*>((short*)out + (unsigned)n * HIDDEN + l5 * 8) = o;
    }
}

// ---------------- bf16 MFMA GEMM: C[M][256] = act(A[M][K] @ W) ----------------
// 64x64 tile, 4 waves 2x2, BK=64 (2 mfma-k-steps per barrier pair).

#define GBM 64
#define GBN 64
#define GBK 64

__global__ __launch_bounds__(256) void gemm_bf16_kernel(
    const bf16_t* __restrict__ A, const bf16_t* __restrict__ Wt,
    const float* __restrict__ bias, bf16_t* __restrict__ C,
    int M, int K,
    const float* __restrict__ bn_g, const float* __restrict__ bn_b,
    const float* __restrict__ bn_m, const float* __restrict__ bn_v, int do_bn)
{
    __shared__ short As[GBM][GBK + 8];   // 72 shorts = 144B row stride
    __shared__ short Bs[GBN][GBK + 8];
    __shared__ short Cs[GBM][72];

    int tid = threadIdx.x;
    int lane = tid & 63;
    int wave = tid >> 6;
    int wr = wave >> 1, wc = wave & 1;
    int row0 = blockIdx.x * GBM, col0 = blockIdx.y * GBN;

    int lrow = tid >> 3, lchunk = tid & 7;   // 32 rows x 8 chunks per pass, 2 passes

    const short* Ab = (const short*)A;
    const short* Wb = (const short*)Wt;

    f32x4 acc[2][2] = {};

    for (int k0 = 0; k0 < K; k0 += GBK) {
        #pragma unroll
        for (int rr = 0; rr < 2; rr++) {
            int r = lrow + rr * 32;
            int arow = row0 + r;
            bf16x8 av = {};
            if (arow < M)
                av = *reinterpret_cast<const bf16x8*>(Ab + (size_t)arow * K + k0 + lchunk * 8);
            *reinterpret_cast<bf16x8*>(&As[r][lchunk * 8]) = av;
            bf16x8 bv = *reinterpret_cast<const bf16x8*>(Wb + (size_t)(col0 + r) * K + k0 + lchunk * 8);
            *reinterpret_cast<bf16x8*>(&Bs[r][lchunk * 8]) = bv;
        }
        __syncthreads();

        int fr = lane & 15, fk = (lane >> 4) * 8;
        #pragma unroll
        for (int ks = 0; ks < 2; ks++) {
            bf16x8 a0 = *reinterpret_cast<const bf16x8*>(&As[wr * 32 + fr][fk + ks * 32]);
            bf16x8 a1 = *reinterpret_cast<const bf16x8*>(&As[wr * 32 + 16 + fr][fk + ks * 32]);
            bf16x8 b0 = *reinterpret_cast<const bf16x8*>(&Bs[wc * 32 + fr][fk + ks * 32]);
            bf16x8 b1 = *reinterpret_cast<const bf16x8*>(&Bs[wc * 32 + 16 + fr][fk + ks * 32]);
            acc[0][0] = __builtin_amdgcn_mfma_f32_16x16x32_bf16(a0, b0, acc[0][0], 0, 0, 0);
            acc[0][1] = __builtin_amdgcn_mfma_f32_16x16x32_bf16(a0, b1, acc[0][1], 0, 0, 0);
            acc[1][0] = __builtin_amdgcn_mfma_f32_16x16x32_bf16(a1, b0, acc[1][0], 0, 0, 0);
            acc[1][1] = __builtin_amdgcn_mfma_f32_16x16x32_bf16(a1, b1, acc[1][1], 0, 0, 0);
        }
        __syncthreads();
    }

    #pragma unroll
    for (int m = 0; m < 2; m++) {
        #pragma unroll
        for (int n = 0; n < 2; n++) {
            int rl = wr * 32 + m * 16 + (lane >> 4) * 4;
            int cl = wc * 32 + n * 16 + (lane & 15);
            int c = col0 + cl;
            float bi = bias[c];
            #pragma unroll
            for (int r = 0; r < 4; r++) {
                float v = acc[m][n][r] + bi;
                v = fmaxf(v, 0.f);
                if (do_bn) v = (v - bn_m[c]) * rsqrtf(bn_v[c] + 1e-5f) * bn_g[c] + bn_b[c];
                Cs[rl + r][cl] = f2bfb(v);
            }
        }
    }
    __syncthreads();
    int lr = tid >> 2, lc = tid & 3;
    int r = row0 + lr;
    if (r < M) {
        bf16x8 c0 = *reinterpret_cast<const bf16x8*>(&Cs[lr][lc * 16]);
        bf16x8 c1 = *reinterpret_cast<const bf16x8*>(&Cs[lr][lc * 16 + 8]);
        short* Cb = (short*)C;
        *reinterpret_cast<bf16x8*>(Cb + (size_t)r * HIDDEN + col0 + lc * 16) = c0;
        *reinterpret_cast<bf16x8*>(Cb + (size_t)r * HIDDEN + col0 + lc * 16 + 8) = c1;
    }
}

// ---------------- Pool: half-wave per node row, 16B/lane, LDS cross-wave reduce ----------------

__global__ __launch_bounds__(256) void pool_kernel(const bf16_t* __restrict__ h,
                                                   const int* __restrict__ batch,
                                                   float* __restrict__ pooled) {
    __shared__ int sbs[2];
    __shared__ float red[4][HIDDEN];
    int g = blockIdx.x;
    if (threadIdx.x == 0) {
        int lo = 0, hi = N_NODES;
        while (lo < hi) { int mid = (lo + hi) >> 1; if (batch[mid] < g) lo = mid + 1; else hi = mid; }
        sbs[0] = lo;
        hi = N_NODES;
        while (lo < hi) { int mid = (lo + hi) >> 1; if (batch[mid] < g + 1) lo = mid + 1; else hi = mid; }
        sbs[1] = lo;
    }
    __syncthreads();
    int sbeg = sbs[0], send = sbs[1];
    int w = threadIdx.x >> 6, lane = threadIdx.x & 63;
    int half = lane >> 5, l5 = lane & 31;
    const short* hb = (const short*)h;
    float acc[8] = {};
    for (int n = sbeg + w * 2 + half; n < send; n += 8) {
        bf16x8 v = *reinterpret_cast<const bf16x8*>(hb + (size_t)n * HIDDEN + l5 * 8);
        #pragma unroll
        for (int j = 0; j < 8; j++) acc[j] += bfb2f(v[j]);
    }
    #pragma unroll
    for (int j = 0; j < 8; j++) acc[j] += __shfl_xor(acc[j], 32);
    if (half == 0) {
        #pragma unroll
        for (int j = 0; j < 8; j++) red[w][l5 * 8 + j] = acc[j];
    }
    __syncthreads();
    int t = threadIdx.x;
    float s = red[0][t] + red[1][t] + red[2][t] + red[3][t];
    float cnt = (float)(send - sbeg);
    pooled[g * HIDDEN + t] = s / fmaxf(cnt, 1.f);
}

// ---------------- Head ----------------

__global__ void head_kernel(const float* __restrict__ pooled,
                            const float* __restrict__ w1, const float* __restrict__ b1,
                            const float* __restrict__ w2, const float* __restrict__ b2,
                            float* __restrict__ out) {
    int g = blockIdx.x, t = threadIdx.x;
    __shared__ float p[HIDDEN];
    __shared__ float h1[HIDDEN];
    __shared__ float lg[N_CLASSES];
    p[t] = pooled[g * HIDDEN + t];
    __syncthreads();
    float acc = b1[t];
    for (int k = 0; k < HIDDEN; k++) acc += p[k] * w1[k * HIDDEN + t];
    h1[t] = fmaxf(acc, 0.f);
    __syncthreads();
    if (t < N_CLASSES) {
        float a = b2[t];
        for (int k = 0; k < HIDDEN; k++) a += h1[k] * w2[k * N_CLASSES + t];
        lg[t] = a;
    }
    __syncthreads();
    if (t == 0) {
        float mx = lg[0];
        for (int j = 1; j < N_CLASSES; j++) mx = fmaxf(mx, lg[j]);
        float se = 0.f;
        for (int j = 0; j < N_CLASSES; j++) se += expf(lg[j] - mx);
        float lse = mx + logf(se);
        for (int j = 0; j < N_CLASSES; j++) out[g * N_CLASSES + j] = lg[j] - lse;
    }
}

// ---------------- Launch ----------------

extern "C" void kernel_launch(void* const* d_in, const int* in_sizes, int n_in,
                              void* d_out, int out_size, void* d_ws, size_t ws_size,
                              hipStream_t stream) {
    const float* x       = (const float*)d_in[0];
    const int*   ei      = (const int*)d_in[1];     // int32 on device (harness contract)
    const int*   batch   = (const int*)d_in[2];
    const float* c1_w0   = (const float*)d_in[3];
    const float* c1_b0   = (const float*)d_in[4];
    const float* c1_w1   = (const float*)d_in[5];
    const float* c1_b1   = (const float*)d_in[6];
    const float* c1_g    = (const float*)d_in[7];
    const float* c1_be   = (const float*)d_in[8];
    const float* c1_m    = (const float*)d_in[9];
    const float* c1_v    = (const float*)d_in[10];
    const float* cs_w0   = (const float*)d_in[11];
    const float* cs_b0   = (const float*)d_in[12];
    const float* cs_w1   = (const float*)d_in[13];
    const float* cs_b1   = (const float*)d_in[14];
    const float* cs_g    = (const float*)d_in[15];
    const float* cs_be   = (const float*)d_in[16];
    const float* cs_m    = (const float*)d_in[17];
    const float* cs_v    = (const float*)d_in[18];
    const float* eps     = (const float*)d_in[19];
    const float* lin1_w  = (const float*)d_in[20];
    const float* lin1_b  = (const float*)d_in[21];
    const float* lin2_w  = (const float*)d_in[22];
    const float* lin2_b  = (const float*)d_in[23];

    char* ws = (char*)d_ws;
    size_t off = 0;
    auto alloc = [&](size_t bytes) -> void* {
        void* p = ws + off;
        off += (bytes + 255) & ~(size_t)255;
        return p;
    };

    unsigned* deg      = (unsigned*)alloc(N_NODES * 4);
    unsigned* rowptr   = (unsigned*)alloc((N_NODES + 1) * 4);
    unsigned* cursor   = (unsigned*)alloc(N_NODES * 4);
    unsigned* blocksum = (unsigned*)alloc(SCAN_NB * 4);
    int*      adj      = (int*)alloc(N_EDGES * 4);
    bf16_t*   Wt       = (bf16_t*)alloc((size_t)(32768 + 7 * 65536) * 2);
    bf16_t*   B1       = (bf16_t*)alloc((size_t)N_NODES * HIDDEN * 2);
    bf16_t*   B2       = (bf16_t*)alloc((size_t)N_NODES * HIDDEN * 2);
    bf16_t*   B3       = (bf16_t*)alloc((size_t)N_NODES * HIDDEN * 2);
    float*    pooled   = (float*)alloc(N_GRAPHS * HIDDEN * 4);

    bf16_t* wt_10 = Wt;                       // c1_w0^T  [256][128]
    bf16_t* wt_11 = Wt + 32768;               // c1_w1^T  [256][256]
    auto wt_c0 = [&](int i) { return Wt + 32768 + (size_t)(1 + 2 * i) * 65536; };
    auto wt_c1 = [&](int i) { return Wt + 32768 + (size_t)(2 + 2 * i) * 65536; };

    hipMemsetAsync(deg, 0, N_NODES * 4, stream);

    int eb = (N_EDGES + 255) / 256;
    count_deg_kernel<<<eb, 256, 0, stream>>>(ei, deg);
    scan_a_kernel<<<SCAN_NB, 256, 0, stream>>>(deg, rowptr, blocksum);
    scan_b_kernel<<<1, 256, 0, stream>>>(blocksum);
    scan_c_kernel<<<SCAN_NB, 256, 0, stream>>>(rowptr, blocksum, cursor);
    fill_adj_kernel<<<eb, 256, 0, stream>>>(ei, cursor, adj);

    prep_weights_kernel<<<dim3(8, 8, 8), 256, 0, stream>>>(c1_w0, c1_w1, cs_w0, cs_w1, Wt);

    dim3 ggrid((N_NODES + GBM - 1) / GBM, HIDDEN / GBN);
    int ab = (N_NODES + 3) / 4;

    // Layer 1 (F=128)
    aggregate1_kernel<<<ab, 256, 0, stream>>>(x, adj, rowptr, eps, B1);
    gemm_bf16_kernel<<<ggrid, 256, 0, stream>>>(B1, wt_10, c1_b0, B2, N_NODES, N_FEAT,
                                                nullptr, nullptr, nullptr, nullptr, 0);
    gemm_bf16_kernel<<<ggrid, 256, 0, stream>>>(B2, wt_11, c1_b1, B3, N_NODES, HIDDEN,
                                                c1_g, c1_be, c1_m, c1_v, 1);

    // Layers 2..4 (F=256)
    for (int i = 0; i < 3; i++) {
        aggregate2_kernel<<<ab, 256, 0, stream>>>(B3, adj, rowptr, eps, i + 1, B1);
        gemm_bf16_kernel<<<ggrid, 256, 0, stream>>>(B1, wt_c0(i), cs_b0 + i * HIDDEN, B2,
                                                    N_NODES, HIDDEN,
                                                    nullptr, nullptr, nullptr, nullptr, 0);
        gemm_bf16_kernel<<<ggrid, 256, 0, stream>>>(B2, wt_c1(i), cs_b1 + i * HIDDEN, B3,
                                                    N_NODES, HIDDEN,
                                                    cs_g + i * HIDDEN, cs_be + i * HIDDEN,
                                                    cs_m + i * HIDDEN, cs_v + i * HIDDEN, 1);
    }

    pool_kernel<<<N_GRAPHS, 256, 0, stream>>>(B3, batch, pooled);
    head_kernel<<<N_GRAPHS, HIDDEN, 0, stream>>>(pooled, lin1_w, lin1_b, lin2_w, lin2_b, (float*)d_out);
}

// Round 6
// 523.060 us; speedup vs baseline: 3.0550x; 1.0930x over previous
//
#include <hip/hip_runtime.h>
#include <hip/hip_bf16.h>

#define N_NODES 50000
#define N_EDGES 800000
#define N_FEAT 128
#define HIDDEN 256
#define N_GRAPHS 256
#define N_CLASSES 10
#define SCAN_NB ((N_NODES + 255) / 256)   // 196 scan blocks

typedef __hip_bfloat16 bf16_t;
typedef short bf16x8 __attribute__((ext_vector_type(8)));
typedef float f32x4 __attribute__((ext_vector_type(4)));

__device__ inline float bfb2f(short s) {
    unsigned u = ((unsigned)(unsigned short)s) << 16;
    float f; __builtin_memcpy(&f, &u, 4); return f;
}
__device__ inline short f2bfb(float f) {
    bf16_t b = __float2bfloat16(f);
    short s; __builtin_memcpy(&s, &b, 2); return s;
}

// ---------------- CSR build ----------------

__global__ void count_deg_kernel(const int* __restrict__ ei, unsigned* __restrict__ deg) {
    int e = blockIdx.x * blockDim.x + threadIdx.x;
    if (e < N_EDGES) atomicAdd(&deg[ei[N_EDGES + e]], 1u);
}

__global__ __launch_bounds__(256) void scan_a_kernel(const unsigned* __restrict__ deg,
                                                     unsigned* __restrict__ rowptr,
                                                     unsigned* __restrict__ blocksum) {
    __shared__ unsigned tmp[256];
    int t = threadIdx.x;
    int g = blockIdx.x * 256 + t;
    unsigned v = (g < N_NODES) ? deg[g] : 0u;
    tmp[t] = v;
    __syncthreads();
    #pragma unroll
    for (int off = 1; off < 256; off <<= 1) {
        unsigned add = (t >= off) ? tmp[t - off] : 0u;
        __syncthreads();
        tmp[t] += add;
        __syncthreads();
    }
    if (g < N_NODES) rowptr[g] = tmp[t] - v;           // exclusive (pre-offset)
    if (t == 255) blocksum[blockIdx.x] = tmp[t];
}

__global__ __launch_bounds__(256) void scan_b_kernel(unsigned* __restrict__ blocksum) {
    __shared__ unsigned tmp[256];
    int t = threadIdx.x;
    unsigned v = (t < SCAN_NB) ? blocksum[t] : 0u;
    tmp[t] = v;
    __syncthreads();
    #pragma unroll
    for (int off = 1; off < 256; off <<= 1) {
        unsigned add = (t >= off) ? tmp[t - off] : 0u;
        __syncthreads();
        tmp[t] += add;
        __syncthreads();
    }
    if (t < SCAN_NB) blocksum[t] = tmp[t] - v;         // exclusive block offsets
}

__global__ __launch_bounds__(256) void scan_c_kernel(unsigned* __restrict__ rowptr,
                                                     const unsigned* __restrict__ blocksum,
                                                     unsigned* __restrict__ cursor) {
    int g = blockIdx.x * 256 + threadIdx.x;
    if (g < N_NODES) {
        unsigned r = rowptr[g] + blocksum[blockIdx.x];
        rowptr[g] = r;
        cursor[g] = r;
    }
    if (g == 0) rowptr[N_NODES] = N_EDGES;
}

__global__ void fill_adj_kernel(const int* __restrict__ ei, unsigned* __restrict__ cursor,
                                int* __restrict__ adj) {
    int e = blockIdx.x * blockDim.x + threadIdx.x;
    if (e < N_EDGES) {
        int src = ei[e];
        int dst = ei[N_EDGES + e];
        unsigned pos = atomicAdd(&cursor[dst], 1u);
        adj[pos] = src;
    }
}

// ---------------- x fp32 -> bf16 convert (halves layer-1 gather bytes) ----------------

__global__ __launch_bounds__(256) void convert_x_kernel(const float* __restrict__ x,
                                                        bf16_t* __restrict__ xb) {
    int i = blockIdx.x * 256 + threadIdx.x;
    if (i < N_NODES * N_FEAT / 4) {
        float4 v = reinterpret_cast<const float4*>(x)[i];
        short4 o;
        o.x = f2bfb(v.x); o.y = f2bfb(v.y); o.z = f2bfb(v.z); o.w = f2bfb(v.w);
        reinterpret_cast<short4*>(xb)[i] = o;
    }
}

// ---------------- Weight prep: fp32 W[K][256] -> bf16 Wt[256][K] ----------------

__global__ __launch_bounds__(256) void prep_weights_kernel(
    const float* __restrict__ c1_w0, const float* __restrict__ c1_w1,
    const float* __restrict__ cs_w0, const float* __restrict__ cs_w1,
    bf16_t* __restrict__ wt)
{
    __shared__ float T[32][33];
    int z = blockIdx.z;
    const float* src; int K; size_t off;
    if (z == 0)      { src = c1_w0; K = N_FEAT;  off = 0; }
    else if (z == 1) { src = c1_w1; K = HIDDEN;  off = 32768; }
    else {
        int i = (z - 2) >> 1;
        src = (((z - 2) & 1) ? cs_w1 : cs_w0) + (size_t)i * HIDDEN * HIDDEN;
        K = HIDDEN;
        off = 32768 + (size_t)(z - 1) * 65536;
    }
    int k0 = blockIdx.x * 32, n0 = blockIdx.y * 32;
    if (k0 >= K) return;
    int t = threadIdx.x;
    int r = t >> 3, c4 = (t & 7) * 4;
    float4 v = *reinterpret_cast<const float4*>(src + (size_t)(k0 + r) * HIDDEN + n0 + c4);
    T[r][c4 + 0] = v.x; T[r][c4 + 1] = v.y; T[r][c4 + 2] = v.z; T[r][c4 + 3] = v.w;
    __syncthreads();
    int n = t >> 3, kc = (t & 7) * 4;
    short4 o;
    o.x = f2bfb(T[kc + 0][n]); o.y = f2bfb(T[kc + 1][n]);
    o.z = f2bfb(T[kc + 2][n]); o.w = f2bfb(T[kc + 3][n]);
    *reinterpret_cast<short4*>((short*)wt + off + (size_t)(n0 + n) * K + k0 + kc) = o;
}

// ---------------- Aggregation layer 1: bf16 xb[N][128] -> bf16 out[N][128] ----------------
// One wave per node; quarter-wave (16 lanes x 16B) per edge, 8 edges in flight.

__global__ __launch_bounds__(256) void aggregate1_kernel(
    const bf16_t* __restrict__ xb, const int* __restrict__ adj,
    const unsigned* __restrict__ rowptr, const float* __restrict__ eps_arr,
    bf16_t* __restrict__ out)
{
    int w = threadIdx.x >> 6, lane = threadIdx.x & 63;
    int n = blockIdx.x * 4 + w;
    if (n >= N_NODES) return;
    int q = lane >> 4, l4 = lane & 15;
    unsigned beg = rowptr[n], end = rowptr[n + 1];
    const short* xs = (const short*)xb;
    float acc[8] = {};
    unsigned e = beg;
    for (; e + 8 <= end; e += 8) {
        int s0 = adj[e + q];
        int s1 = adj[e + 4 + q];
        bf16x8 v0 = *reinterpret_cast<const bf16x8*>(xs + (unsigned)s0 * N_FEAT + l4 * 8);
        bf16x8 v1 = *reinterpret_cast<const bf16x8*>(xs + (unsigned)s1 * N_FEAT + l4 * 8);
        #pragma unroll
        for (int j = 0; j < 8; j++) acc[j] += bfb2f(v0[j]) + bfb2f(v1[j]);
    }
    for (; e + 4 <= end; e += 4) {
        int s0 = adj[e + q];
        bf16x8 v0 = *reinterpret_cast<const bf16x8*>(xs + (unsigned)s0 * N_FEAT + l4 * 8);
        #pragma unroll
        for (int j = 0; j < 8; j++) acc[j] += bfb2f(v0[j]);
    }
    int rem = (int)(end - e);
    if (q < rem) {
        bf16x8 v0 = *reinterpret_cast<const bf16x8*>(xs + (unsigned)adj[e + q] * N_FEAT + l4 * 8);
        #pragma unroll
        for (int j = 0; j < 8; j++) acc[j] += bfb2f(v0[j]);
    }
    if (q == 0) {
        bf16x8 sv = *reinterpret_cast<const bf16x8*>(xs + (unsigned)n * N_FEAT + l4 * 8);
        float ep = 1.f + eps_arr[0];
        #pragma unroll
        for (int j = 0; j < 8; j++) acc[j] += ep * bfb2f(sv[j]);
    }
    #pragma unroll
    for (int j = 0; j < 8; j++) {
        acc[j] += __shfl_xor(acc[j], 16);
        acc[j] += __shfl_xor(acc[j], 32);
    }
    if (lane < 16) {
        bf16x8 o;
        #pragma unroll
        for (int j = 0; j < 8; j++) o[j] = f2bfb(acc[j]);
        *reinterpret_cast<bf16x8*>((short*)out + (unsigned)n * N_FEAT + l4 * 8) = o;
    }
}

// ---------------- Aggregation layers 2-4: bf16 [N][256] -> bf16 [N][256] ----------------
// Half-wave (32 lanes x 16B) per edge, 8 edges in flight.

__global__ __launch_bounds__(256) void aggregate2_kernel(
    const bf16_t* __restrict__ x, const int* __restrict__ adj,
    const unsigned* __restrict__ rowptr, const float* __restrict__ eps_arr, int eps_idx,
    bf16_t* __restrict__ out)
{
    int w = threadIdx.x >> 6, lane = threadIdx.x & 63;
    int n = blockIdx.x * 4 + w;
    if (n >= N_NODES) return;
    int half = lane >> 5, l5 = lane & 31;
    unsigned beg = rowptr[n], end = rowptr[n + 1];
    const short* xs = (const short*)x;
    float acc[8] = {};
    unsigned e = beg;
    for (; e + 8 <= end; e += 8) {
        int s0 = adj[e + half];
        int s1 = adj[e + 2 + half];
        int s2 = adj[e + 4 + half];
        int s3 = adj[e + 6 + half];
        bf16x8 v0 = *reinterpret_cast<const bf16x8*>(xs + (unsigned)s0 * HIDDEN + l5 * 8);
        bf16x8 v1 = *reinterpret_cast<const bf16x8*>(xs + (unsigned)s1 * HIDDEN + l5 * 8);
        bf16x8 v2 = *reinterpret_cast<const bf16x8*>(xs + (unsigned)s2 * HIDDEN + l5 * 8);
        bf16x8 v3 = *reinterpret_cast<const bf16x8*>(xs + (unsigned)s3 * HIDDEN + l5 * 8);
        #pragma unroll
        for (int j = 0; j < 8; j++)
            acc[j] += (bfb2f(v0[j]) + bfb2f(v1[j])) + (bfb2f(v2[j]) + bfb2f(v3[j]));
    }
    for (; e + 2 <= end; e += 2) {
        int s0 = adj[e + half];
        bf16x8 v0 = *reinterpret_cast<const bf16x8*>(xs + (unsigned)s0 * HIDDEN + l5 * 8);
        #pragma unroll
        for (int j = 0; j < 8; j++) acc[j] += bfb2f(v0[j]);
    }
    if (e < end && half == 0) {
        bf16x8 v0 = *reinterpret_cast<const bf16x8*>(xs + (unsigned)adj[e] * HIDDEN + l5 * 8);
        #pragma unroll
        for (int j = 0; j < 8; j++) acc[j] += bfb2f(v0[j]);
    }
    if (half == 0) {
        bf16x8 sv = *reinterpret_cast<const bf16x8*>(xs + (unsigned)n * HIDDEN + l5 * 8);
        float ep = 1.f + eps_arr[eps_idx];
        #pragma unroll
        for (int j = 0; j < 8; j++) acc[j] += ep * bfb2f(sv[j]);
    }
    #pragma unroll
    for (int j = 0; j < 8; j++) acc[j] += __shfl_xor(acc[j], 32);
    if (half == 0) {
        bf16x8 o;
        #pragma unroll
        for (int j = 0; j < 8; j++) o[j] = f2bfb(acc[j]);
        *reinterpret_cast<bf16x8*>((short*)out + (unsigned)n * HIDDEN + l5 * 8) = o;
    }
}

// ---------------- bf16 MFMA GEMM: C[M][256] = act(A[M][K] @ W) ----------------
// 128x128 tile, 512 threads (8 waves, 2x4), BK=64. Wave tile 64x32, 4x2 mfma frags.
// Epilogue Cs overlaid on As/Bs LDS.

#define GBM 128
#define GBN 128
#define GBK 64

__global__ __launch_bounds__(512) void gemm_bf16_kernel(
    const bf16_t* __restrict__ A, const bf16_t* __restrict__ Wt,
    const float* __restrict__ bias, bf16_t* __restrict__ C,
    int M, int K,
    const float* __restrict__ bn_g, const float* __restrict__ bn_b,
    const float* __restrict__ bn_m, const float* __restrict__ bn_v, int do_bn)
{
    __shared__ short lds[18432];                       // 36.9 KB
    short (*As)[72] = reinterpret_cast<short(*)[72]>(lds);          // [128][72]
    short (*Bs)[72] = reinterpret_cast<short(*)[72]>(lds + 9216);   // [128][72]
    short (*Cs)[136] = reinterpret_cast<short(*)[136]>(lds);        // [128][136] (overlay)

    int tid = threadIdx.x;
    int lane = tid & 63;
    int wave = tid >> 6;
    int wr = wave >> 2, wc = wave & 3;                 // 2 x 4 wave grid
    int row0 = blockIdx.x * GBM, col0 = blockIdx.y * GBN;

    int lrow = tid >> 3, lch = tid & 7;                // 64 rows x 8 chunks per pass, 2 passes

    const short* Ab = (const short*)A;
    const short* Wb = (const short*)Wt;

    f32x4 acc[4][2] = {};

    for (int k0 = 0; k0 < K; k0 += GBK) {
        #pragma unroll
        for (int rr = 0; rr < 2; rr++) {
            int r = lrow + rr * 64;
            int arow = row0 + r;
            bf16x8 av = {};
            if (arow < M)
                av = *reinterpret_cast<const bf16x8*>(Ab + (size_t)arow * K + k0 + lch * 8);
            *reinterpret_cast<bf16x8*>(&As[r][lch * 8]) = av;
            bf16x8 bv = *reinterpret_cast<const bf16x8*>(Wb + (size_t)(col0 + r) * K + k0 + lch * 8);
            *reinterpret_cast<bf16x8*>(&Bs[r][lch * 8]) = bv;
        }
        __syncthreads();

        int fr = lane & 15, fk = (lane >> 4) * 8;
        #pragma unroll
        for (int ks = 0; ks < 2; ks++) {
            bf16x8 a[4], b[2];
            #pragma unroll
            for (int m = 0; m < 4; m++)
                a[m] = *reinterpret_cast<const bf16x8*>(&As[wr * 64 + m * 16 + fr][ks * 32 + fk]);
            #pragma unroll
            for (int n = 0; n < 2; n++)
                b[n] = *reinterpret_cast<const bf16x8*>(&Bs[wc * 32 + n * 16 + fr][ks * 32 + fk]);
            #pragma unroll
            for (int m = 0; m < 4; m++)
                #pragma unroll
                for (int n = 0; n < 2; n++)
                    acc[m][n] = __builtin_amdgcn_mfma_f32_16x16x32_bf16(a[m], b[n], acc[m][n], 0, 0, 0);
        }
        __syncthreads();
    }

    // epilogue: bias + relu (+ BN) -> bf16 -> Cs (overlaid) -> coalesced global stores
    #pragma unroll
    for (int m = 0; m < 4; m++) {
        #pragma unroll
        for (int n = 0; n < 2; n++) {
            int rl = wr * 64 + m * 16 + (lane >> 4) * 4;
            int cl = wc * 32 + n * 16 + (lane & 15);
            int c = col0 + cl;
            float bi = bias[c];
            #pragma unroll
            for (int r = 0; r < 4; r++) {
                float v = acc[m][n][r] + bi;
                v = fmaxf(v, 0.f);
                if (do_bn) v = (v - bn_m[c]) * rsqrtf(bn_v[c] + 1e-5f) * bn_g[c] + bn_b[c];
                Cs[rl + r][cl] = f2bfb(v);
            }
        }
    }
    __syncthreads();
    int lr = tid >> 2, c16 = tid & 3;
    int r = row0 + lr;
    if (r < M) {
        short* Cb = (short*)C;
        #pragma unroll
        for (int cc = 0; cc < 4; cc++) {
            int ch = c16 + cc * 4;                     // 0..15 chunks of 8 shorts
            bf16x8 cv = *reinterpret_cast<const bf16x8*>(&Cs[lr][ch * 8]);
            *reinterpret_cast<bf16x8*>(Cb + (size_t)r * HIDDEN + col0 + ch * 8) = cv;
        }
    }
}

// ---------------- Pool: half-wave per node row, 16B/lane, LDS cross-wave reduce ----------------

__global__ __launch_bounds__(256) void pool_kernel(const bf16_t* __restrict__ h,
                                                   const int* __restrict__ batch,
                                                   float* __restrict__ pooled) {
    __shared__ int sbs[2];
    __shared__ float red[4][HIDDEN];
    int g = blockIdx.x;
    if (threadIdx.x == 0) {
        int lo = 0, hi = N_NODES;
        while (lo < hi) { int mid = (lo + hi) >> 1; if (batch[mid] < g) lo = mid + 1; else hi = mid; }
        sbs[0] = lo;
        hi = N_NODES;
        while (lo < hi) { int mid = (lo + hi) >> 1; if (batch[mid] < g + 1) lo = mid + 1; else hi = mid; }
        sbs[1] = lo;
    }
    __syncthreads();
    int sbeg = sbs[0], send = sbs[1];
    int w = threadIdx.x >> 6, lane = threadIdx.x & 63;
    int half = lane >> 5, l5 = lane & 31;
    const short* hb = (const short*)h;
    float acc[8] = {};
    for (int n = sbeg + w * 2 + half; n < send; n += 8) {
        bf16x8 v = *reinterpret_cast<const bf16x8*>(hb + (size_t)n * HIDDEN + l5 * 8);
        #pragma unroll
        for (int j = 0; j < 8; j++) acc[j] += bfb2f(v[j]);
    }
    #pragma unroll
    for (int j = 0; j < 8; j++) acc[j] += __shfl_xor(acc[j], 32);
    if (half == 0) {
        #pragma unroll
        for (int j = 0; j < 8; j++) red[w][l5 * 8 + j] = acc[j];
    }
    __syncthreads();
    int t = threadIdx.x;
    float s = red[0][t] + red[1][t] + red[2][t] + red[3][t];
    float cnt = (float)(send - sbeg);
    pooled[g * HIDDEN + t] = s / fmaxf(cnt, 1.f);
}

// ---------------- Head ----------------

__global__ void head_kernel(const float* __restrict__ pooled,
                            const float* __restrict__ w1, const float* __restrict__ b1,
                            const float* __restrict__ w2, const float* __restrict__ b2,
                            float* __restrict__ out) {
    int g = blockIdx.x, t = threadIdx.x;
    __shared__ float p[HIDDEN];
    __shared__ float h1[HIDDEN];
    __shared__ float lg[N_CLASSES];
    p[t] = pooled[g * HIDDEN + t];
    __syncthreads();
    float acc = b1[t];
    for (int k = 0; k < HIDDEN; k++) acc += p[k] * w1[k * HIDDEN + t];
    h1[t] = fmaxf(acc, 0.f);
    __syncthreads();
    if (t < N_CLASSES) {
        float a = b2[t];
        for (int k = 0; k < HIDDEN; k++) a += h1[k] * w2[k * N_CLASSES + t];
        lg[t] = a;
    }
    __syncthreads();
    if (t == 0) {
        float mx = lg[0];
        for (int j = 1; j < N_CLASSES; j++) mx = fmaxf(mx, lg[j]);
        float se = 0.f;
        for (int j = 0; j < N_CLASSES; j++) se += expf(lg[j] - mx);
        float lse = mx + logf(se);
        for (int j = 0; j < N_CLASSES; j++) out[g * N_CLASSES + j] = lg[j] - lse;
    }
}

// ---------------- Launch ----------------

extern "C" void kernel_launch(void* const* d_in, const int* in_sizes, int n_in,
                              void* d_out, int out_size, void* d_ws, size_t ws_size,
                              hipStream_t stream) {
    const float* x       = (const float*)d_in[0];
    const int*   ei      = (const int*)d_in[1];     // int32 on device (harness contract)
    const int*   batch   = (const int*)d_in[2];
    const float* c1_w0   = (const float*)d_in[3];
    const float* c1_b0   = (const float*)d_in[4];
    const float* c1_w1   = (const float*)d_in[5];
    const float* c1_b1   = (const float*)d_in[6];
    const float* c1_g    = (const float*)d_in[7];
    const float* c1_be   = (const float*)d_in[8];
    const float* c1_m    = (const float*)d_in[9];
    const float* c1_v    = (const float*)d_in[10];
    const float* cs_w0   = (const float*)d_in[11];
    const float* cs_b0   = (const float*)d_in[12];
    const float* cs_w1   = (const float*)d_in[13];
    const float* cs_b1   = (const float*)d_in[14];
    const float* cs_g    = (const float*)d_in[15];
    const float* cs_be   = (const float*)d_in[16];
    const float* cs_m    = (const float*)d_in[17];
    const float* cs_v    = (const float*)d_in[18];
    const float* eps     = (const float*)d_in[19];
    const float* lin1_w  = (const float*)d_in[20];
    const float* lin1_b  = (const float*)d_in[21];
    const float* lin2_w  = (const float*)d_in[22];
    const float* lin2_b  = (const float*)d_in[23];

    char* ws = (char*)d_ws;
    size_t off = 0;
    auto alloc = [&](size_t bytes) -> void* {
        void* p = ws + off;
        off += (bytes + 255) & ~(size_t)255;
        return p;
    };

    unsigned* deg      = (unsigned*)alloc(N_NODES * 4);
    unsigned* rowptr   = (unsigned*)alloc((N_NODES + 1) * 4);
    unsigned* cursor   = (unsigned*)alloc(N_NODES * 4);
    unsigned* blocksum = (unsigned*)alloc(SCAN_NB * 4);
    int*      adj      = (int*)alloc(N_EDGES * 4);
    bf16_t*   Wt       = (bf16_t*)alloc((size_t)(32768 + 7 * 65536) * 2);
    bf16_t*   xb       = (bf16_t*)alloc((size_t)N_NODES * N_FEAT * 2);
    bf16_t*   B1       = (bf16_t*)alloc((size_t)N_NODES * HIDDEN * 2);
    bf16_t*   B2       = (bf16_t*)alloc((size_t)N_NODES * HIDDEN * 2);
    bf16_t*   B3       = (bf16_t*)alloc((size_t)N_NODES * HIDDEN * 2);
    float*    pooled   = (float*)alloc(N_GRAPHS * HIDDEN * 4);

    bf16_t* wt_10 = Wt;                       // c1_w0^T  [256][128]
    bf16_t* wt_11 = Wt + 32768;               // c1_w1^T  [256][256]
    auto wt_c0 = [&](int i) { return Wt + 32768 + (size_t)(1 + 2 * i) * 65536; };
    auto wt_c1 = [&](int i) { return Wt + 32768 + (size_t)(2 + 2 * i) * 65536; };

    hipMemsetAsync(deg, 0, N_NODES * 4, stream);

    int eb = (N_EDGES + 255) / 256;
    count_deg_kernel<<<eb, 256, 0, stream>>>(ei, deg);
    scan_a_kernel<<<SCAN_NB, 256, 0, stream>>>(deg, rowptr, blocksum);
    scan_b_kernel<<<1, 256, 0, stream>>>(blocksum);
    scan_c_kernel<<<SCAN_NB, 256, 0, stream>>>(rowptr, blocksum, cursor);
    fill_adj_kernel<<<eb, 256, 0, stream>>>(ei, cursor, adj);

    convert_x_kernel<<<(N_NODES * N_FEAT / 4 + 255) / 256, 256, 0, stream>>>(x, xb);
    prep_weights_kernel<<<dim3(8, 8, 8), 256, 0, stream>>>(c1_w0, c1_w1, cs_w0, cs_w1, Wt);

    dim3 ggrid((N_NODES + GBM - 1) / GBM, HIDDEN / GBN);
    int ab = (N_NODES + 3) / 4;

    // Layer 1 (F=128)
    aggregate1_kernel<<<ab, 256, 0, stream>>>(xb, adj, rowptr, eps, B1);
    gemm_bf16_kernel<<<ggrid, 512, 0, stream>>>(B1, wt_10, c1_b0, B2, N_NODES, N_FEAT,
                                                nullptr, nullptr, nullptr, nullptr, 0);
    gemm_bf16_kernel<<<ggrid, 512, 0, stream>>>(B2, wt_11, c1_b1, B3, N_NODES, HIDDEN,
                                                c1_g, c1_be, c1_m, c1_v, 1);

    // Layers 2..4 (F=256)
    for (int i = 0; i < 3; i++) {
        aggregate2_kernel<<<ab, 256, 0, stream>>>(B3, adj, rowptr, eps, i + 1, B1);
        gemm_bf16_kernel<<<ggrid, 512, 0, stream>>>(B1, wt_c0(i), cs_b0 + i * HIDDEN, B2,
                                                    N_NODES, HIDDEN,
                                                    nullptr, nullptr, nullptr, nullptr, 0);
        gemm_bf16_kernel<<<ggrid, 512, 0, stream>>>(B2, wt_c1(i), cs_b1 + i * HIDDEN, B3,
                                                    N_NODES, HIDDEN,
                                                    cs_g + i * HIDDEN, cs_be + i * HIDDEN,
                                                    cs_m + i * HIDDEN, cs_v + i * HIDDEN, 1);
    }

    pool_kernel<<<N_GRAPHS, 256, 0, stream>>>(B3, batch, pooled);
    head_kernel<<<N_GRAPHS, HIDDEN, 0, stream>>>(pooled, lin1_w, lin1_b, lin2_w, lin2_b, (float*)d_out);
}